// Round 2
// baseline (1235.963 us; speedup 1.0000x reference)
//
#include <hip/hip_runtime.h>
#include <math.h>

// GCN 2-layer: N=100K nodes, E=3.2M edges (+N self loops), 64 -> 128 -> 64.
// Strategy:
//  - Fold norm: out[d] = dinv[d] * sum_s (dinv[s]*h[s]) + b
//  - Layer 1: aggregate x first (64ch), then GEMM to 128.
//    Layer 2: GEMM to 64ch first, then aggregate. Both gathers are 64ch.
//  - CSR (by dst) built once with int atomics, reused by both layers.
//  - dinv bookkeeping (R1 fix: MODE 2 had a double dinv):
//      A1   = dinv[d] * sum_s dinv[s]*x[s]          (k_scale + agg)
//      a1s  = relu(A1@W1 + b1) * dinv[row]          (GEMM MODE 1: h1 prescaled)
//      h2s  = a1s @ W2                              (GEMM MODE 2: NO extra scale)
//      out  = dinv[d] * sum_s h2s[s] + b2           (agg with bias)

#define IN_C 64
#define HID_C 128
#define OUT_C 64

// ---- CSR build ------------------------------------------------------------

__global__ void k_detect_i64(const int* __restrict__ ei, int e, int* __restrict__ flag) {
  // If buffer holds int64 values (< 2^31), every odd int32 word is 0.
  __shared__ int any;
  if (threadIdx.x == 0) any = 0;
  __syncthreads();
  int lim = min(e, 2048);
  int found = 0;
  for (int i = threadIdx.x; i < lim; i += 256)
    if (ei[2 * i + 1] != 0) found = 1;
  if (found) atomicOr(&any, 1);
  __syncthreads();
  if (threadIdx.x == 0) *flag = any;  // 1 => int32 layout, 0 => int64 layout
}

__global__ void k_init_deg(int* __restrict__ deg, int n) {
  int i = blockIdx.x * blockDim.x + threadIdx.x;
  if (i < n) deg[i] = 1;  // self-loop
}

__global__ void k_count(const int* __restrict__ ei, int e, int n,
                        int* __restrict__ deg, const int* __restrict__ flag) {
  int i = blockIdx.x * blockDim.x + threadIdx.x;
  if (i >= e) return;
  int d;
  if (*flag) d = ei[e + i];
  else       d = (int)(((const long long*)ei)[e + i]);
  d = min(max(d, 0), n - 1);
  atomicAdd(&deg[d], 1);
}

__global__ __launch_bounds__(1024) void k_scan(const int* __restrict__ deg,
    int* __restrict__ row_ptr, int* __restrict__ cursor,
    float* __restrict__ dinv, int n) {
  __shared__ int sums[1024];
  int t = threadIdx.x;
  int chunk = (n + 1023) >> 10;
  int lo = t * chunk;
  int hi = min(lo + chunk, n);
  int s = 0;
  for (int i = lo; i < hi; i++) s += deg[i];
  sums[t] = s;
  __syncthreads();
  for (int off = 1; off < 1024; off <<= 1) {
    int v = (t >= off) ? sums[t - off] : 0;
    __syncthreads();
    sums[t] += v;
    __syncthreads();
  }
  int run = (t == 0) ? 0 : sums[t - 1];
  for (int i = lo; i < hi; i++) {
    int dg = deg[i];
    row_ptr[i] = run;
    cursor[i] = run;
    dinv[i] = rsqrtf((float)dg);
    run += dg;
  }
  if (t == 1023) row_ptr[n] = sums[1023];
}

__global__ void k_scatter(const int* __restrict__ ei, int e, int n,
                          int* __restrict__ cursor, int* __restrict__ col,
                          const int* __restrict__ flag) {
  int i = blockIdx.x * blockDim.x + threadIdx.x;
  int tot = e + n;
  if (i >= tot) return;
  int s, d;
  if (i < e) {
    if (*flag) { s = ei[i]; d = ei[e + i]; }
    else {
      s = (int)(((const long long*)ei)[i]);
      d = (int)(((const long long*)ei)[e + i]);
    }
    s = min(max(s, 0), n - 1);
    d = min(max(d, 0), n - 1);
  } else {
    s = i - e; d = s;  // self-loop
  }
  int pos = atomicAdd(&cursor[d], 1);
  col[pos] = s;
}

// ---- feature prescale -----------------------------------------------------

__global__ void k_scale(const float* __restrict__ x, const float* __restrict__ dinv,
                        float* __restrict__ xs, int total) {
  int i = blockIdx.x * blockDim.x + threadIdx.x;
  if (i < total) xs[i] = x[i] * dinv[i >> 6];  // 64 channels per row
}

// ---- aggregation: one wave per dst node, lane = channel (64ch) ------------

template<bool BIAS>
__global__ __launch_bounds__(256) void k_agg(const float* __restrict__ feat,
    const int* __restrict__ row_ptr, const int* __restrict__ col,
    const float* __restrict__ dinv, const float* __restrict__ bias,
    float* __restrict__ out, int n) {
  int wid = threadIdx.x >> 6;
  int lane = threadIdx.x & 63;
  int d = blockIdx.x * 4 + wid;
  if (d >= n) return;
  int beg = row_ptr[d], end = row_ptr[d + 1];
  float acc = 0.f;
  for (int j0 = beg; j0 < end; j0 += 64) {
    int cnt = min(64, end - j0);
    int idx = (lane < cnt) ? col[j0 + lane] : 0;
    for (int t = 0; t < cnt; t++) {
      int s = __shfl(idx, t);
      acc += feat[(size_t)s * 64 + lane];
    }
  }
  float r = acc * dinv[d];
  if (BIAS) r += bias[lane];
  out[(size_t)d * 64 + lane] = r;
}

// ---- fp32 GEMM: [M,K] @ [K,N], W staged in LDS, 4ch x NT-node reg tile ----
// MODE 1: out = relu(acc + bias[c]) * dinv[row]   (layer-1 epilogue + L2 prescale)
// MODE 2: out = acc                               (plain GEMM; agg applies dinv[d])

template<int K, int N, int MODE>
__global__ __launch_bounds__(256) void k_gemm(const float* __restrict__ A,
    const float* __restrict__ W, const float* __restrict__ bias,
    const float* __restrict__ dinv, float* __restrict__ out, int M) {
  constexpr int TILE_M = 32;
  constexpr int TILE_K = 64;
  constexpr int XS = TILE_K + 4;   // pad: breaks node-stride bank aliasing
  constexpr int CG = N / 4;        // channel groups of 4
  constexpr int NG = 256 / CG;     // node groups
  constexpr int NT = TILE_M / NG;  // nodes per thread
  __shared__ float sW[K * N];
  __shared__ float sX[TILE_M * XS];
  const int t = threadIdx.x;
  for (int i = t; i < K * N / 4; i += 256)
    ((float4*)sW)[i] = ((const float4*)W)[i];
  const int m0 = blockIdx.x * TILE_M;
  const int cg = t % CG, ng = t / CG;
  const int c0 = cg * 4;
  float4 acc[NT];
#pragma unroll
  for (int i = 0; i < NT; i++) acc[i] = make_float4(0.f, 0.f, 0.f, 0.f);
  for (int kt = 0; kt < K; kt += TILE_K) {
    __syncthreads();
    for (int i = t; i < TILE_M * TILE_K / 4; i += 256) {
      int r = i >> 4, q = i & 15;
      int row = m0 + r;
      row = row < M ? row : M - 1;
      *(float4*)&sX[r * XS + q * 4] = *(const float4*)&A[(size_t)row * K + kt + q * 4];
    }
    __syncthreads();
#pragma unroll 4
    for (int k = 0; k < TILE_K; k += 4) {
      float4 w0 = *(float4*)&sW[(kt + k + 0) * N + c0];
      float4 w1 = *(float4*)&sW[(kt + k + 1) * N + c0];
      float4 w2 = *(float4*)&sW[(kt + k + 2) * N + c0];
      float4 w3 = *(float4*)&sW[(kt + k + 3) * N + c0];
#pragma unroll
      for (int i = 0; i < NT; i++) {
        float4 xq = *(float4*)&sX[(ng * NT + i) * XS + k];
        acc[i].x += xq.x * w0.x + xq.y * w1.x + xq.z * w2.x + xq.w * w3.x;
        acc[i].y += xq.x * w0.y + xq.y * w1.y + xq.z * w2.y + xq.w * w3.y;
        acc[i].z += xq.x * w0.z + xq.y * w1.z + xq.z * w2.z + xq.w * w3.z;
        acc[i].w += xq.x * w0.w + xq.y * w1.w + xq.z * w2.w + xq.w * w3.w;
      }
    }
  }
#pragma unroll
  for (int i = 0; i < NT; i++) {
    int nrow = m0 + ng * NT + i;
    if (nrow >= M) continue;
    float4 r = acc[i];
    if (MODE == 1) {
      float s = dinv[nrow];
      r.x = fmaxf(r.x + bias[c0 + 0], 0.f) * s;
      r.y = fmaxf(r.y + bias[c0 + 1], 0.f) * s;
      r.z = fmaxf(r.z + bias[c0 + 2], 0.f) * s;
      r.w = fmaxf(r.w + bias[c0 + 3], 0.f) * s;
    }
    *(float4*)&out[(size_t)nrow * N + c0] = r;
  }
}

// ---- launch ---------------------------------------------------------------

extern "C" void kernel_launch(void* const* d_in, const int* in_sizes, int n_in,
                              void* d_out, int out_size, void* d_ws, size_t ws_size,
                              hipStream_t stream) {
  const float* x  = (const float*)d_in[0];
  const int*   ei = (const int*)d_in[1];
  const float* W1 = (const float*)d_in[2];
  const float* b1 = (const float*)d_in[3];
  const float* W2 = (const float*)d_in[4];
  const float* b2 = (const float*)d_in[5];
  float* out = (float*)d_out;

  const int n = in_sizes[0] / IN_C;   // 100000
  const int e = in_sizes[1] / 2;      // 3200000

  char* p = (char*)d_ws;
  auto alloc = [&](size_t bytes) {
    char* r = p;
    p += (bytes + 255) & ~(size_t)255;
    return r;
  };
  int*   flag    = (int*)alloc(4);
  int*   deg     = (int*)alloc((size_t)n * 4);
  int*   cursor  = (int*)alloc((size_t)n * 4);
  int*   row_ptr = (int*)alloc((size_t)(n + 1) * 4);
  float* dinv    = (float*)alloc((size_t)n * 4);
  int*   col     = (int*)alloc((size_t)(e + n) * 4);
  float* xs      = (float*)alloc((size_t)n * IN_C * 4);   // reused as h2s
  float* A1      = (float*)alloc((size_t)n * IN_C * 4);
  float* a1s     = (float*)alloc((size_t)n * HID_C * 4);
  float* h2s     = xs;  // xs dead after Agg1

  // CSR build
  k_detect_i64<<<1, 256, 0, stream>>>(ei, e, flag);
  k_init_deg<<<(n + 255) / 256, 256, 0, stream>>>(deg, n);
  k_count<<<(e + 255) / 256, 256, 0, stream>>>(ei, e, n, deg, flag);
  k_scan<<<1, 1024, 0, stream>>>(deg, row_ptr, cursor, dinv, n);
  k_scatter<<<(e + n + 255) / 256, 256, 0, stream>>>(ei, e, n, cursor, col, flag);

  // Layer 1: prescale x, aggregate (64ch), GEMM 64->128 (+b1, relu, *dinv)
  k_scale<<<((size_t)n * IN_C + 255) / 256, 256, 0, stream>>>(x, dinv, xs, n * IN_C);
  k_agg<false><<<(n + 3) / 4, 256, 0, stream>>>(xs, row_ptr, col, dinv, nullptr, A1, n);
  k_gemm<IN_C, HID_C, 1><<<(n + 31) / 32, 256, 0, stream>>>(A1, W1, b1, dinv, a1s, n);

  // Layer 2: GEMM 128->64 (plain), aggregate (64ch, *dinv[d], +b2) -> out
  k_gemm<HID_C, OUT_C, 2><<<(n + 31) / 32, 256, 0, stream>>>(a1s, W2, nullptr, dinv, h2s, n);
  k_agg<true><<<(n + 3) / 4, 256, 0, stream>>>(h2s, row_ptr, col, dinv, b2, out, n);
}

// Round 3
// 640.312 us; speedup vs baseline: 1.9303x; 1.9303x over previous
//
#include <hip/hip_runtime.h>
#include <math.h>

// GCN 2-layer: N=100K nodes, E=3.2M edges (+N self loops), 64 -> 128 -> 64.
//  - Fold norm: out[d] = dinv[d] * sum_s (dinv[s]*h[s]) + b
//  - Layer 1: aggregate x first (64ch) then GEMM; layer 2: GEMM then aggregate.
//  - CSR built via bucketed two-phase scatter (R2: the flat atomic scatter had
//    15x HBM write amplification, 294 us — all global writes now coalesced or
//    confined to an L2-resident bucket region; all cursors are LDS atomics).

#define IN_C 64
#define HID_C 128
#define OUT_C 64
#define BSHIFT 9
#define BW (1 << BSHIFT)          // 512 nodes per bucket
#define STAGE_C 16                // staged entries per bucket in k_bucket

// ---- int64/int32 edge layout detection ------------------------------------

__global__ void k_detect_i64(const int* __restrict__ ei, int e, int* __restrict__ flag) {
  __shared__ int any;
  if (threadIdx.x == 0) any = 0;
  __syncthreads();
  int lim = min(e, 2048);
  int found = 0;
  for (int i = threadIdx.x; i < lim; i += 256)
    if (ei[2 * i + 1] != 0) found = 1;
  if (found) atomicOr(&any, 1);
  __syncthreads();
  if (threadIdx.x == 0) *flag = any;  // 1 => int32 layout, 0 => int64 layout
}

__global__ void k_zero(int* __restrict__ p, int cnt) {
  int i = blockIdx.x * blockDim.x + threadIdx.x;
  if (i < cnt) p[i] = 0;
}

// ---- bucket histogram ------------------------------------------------------

__global__ __launch_bounds__(256) void k_bhist(const int* __restrict__ ei, int e, int n,
    int nb, int* __restrict__ bucket_cnt, const int* __restrict__ flag) {
  extern __shared__ int lh[];
  for (int i = threadIdx.x; i < nb; i += 256) lh[i] = 0;
  __syncthreads();
  const int f = *flag;
  for (int i = blockIdx.x * 256 + threadIdx.x; i < e; i += gridDim.x * 256) {
    int d = f ? ei[e + i] : (int)(((const long long*)ei)[e + i]);
    d = min(max(d, 0), n - 1);
    atomicAdd(&lh[d >> BSHIFT], 1);
  }
  __syncthreads();
  for (int i = threadIdx.x; i < nb; i += 256)
    if (lh[i]) atomicAdd(&bucket_cnt[i], lh[i]);
}

// ---- bucket scan: ebase (edges only), cbase (edges+selfloops), gcur --------

__global__ __launch_bounds__(256) void k_bscan(const int* __restrict__ bucket_cnt,
    int nb, int n, int* __restrict__ ebase, int* __restrict__ cbase,
    int* __restrict__ gcur) {
  __shared__ int se[256], sc[256];
  int t = threadIdx.x;
  int c = 0, nodes = 0;
  if (t < nb) {
    c = bucket_cnt[t];
    nodes = min(BW, n - t * BW);
  }
  se[t] = c; sc[t] = c + nodes;
  __syncthreads();
  for (int off = 1; off < 256; off <<= 1) {
    int ve = (t >= off) ? se[t - off] : 0;
    int vc = (t >= off) ? sc[t - off] : 0;
    __syncthreads();
    se[t] += ve; sc[t] += vc;
    __syncthreads();
  }
  if (t < nb) {
    ebase[t + 1] = se[t];
    cbase[t + 1] = sc[t];
    gcur[t] = (t == 0) ? 0 : se[t - 1];
    if (t == 0) { ebase[0] = 0; cbase[0] = 0; }
  }
}

// ---- bucketed edge scatter with LDS staging --------------------------------

__global__ __launch_bounds__(256) void k_bucket(const int* __restrict__ ei, int e, int n,
    int nb, int* __restrict__ gcur, long long* __restrict__ ebuf,
    const int* __restrict__ flag) {
  extern __shared__ int lds[];
  int* cnt = lds;                        // nb ints
  long long* stage = (long long*)(lds + ((nb + 1) & ~1));  // 8B aligned
  const int t = threadIdx.x;
  for (int i = t; i < nb; i += 256) cnt[i] = 0;
  __syncthreads();
  const int f = *flag;
  const int ntiles = (e + 255) >> 8;
  for (int tile = blockIdx.x; tile < ntiles; tile += gridDim.x) {
    int i = tile * 256 + t;
    if (i < e) {
      int s, d;
      if (f) { s = ei[i]; d = ei[e + i]; }
      else {
        s = (int)(((const long long*)ei)[i]);
        d = (int)(((const long long*)ei)[e + i]);
      }
      s = min(max(s, 0), n - 1);
      d = min(max(d, 0), n - 1);
      int b = d >> BSHIFT;
      long long pk = ((long long)d << 32) | (unsigned)s;
      int slot = atomicAdd(&cnt[b], 1);
      if (slot < STAGE_C) stage[b * STAGE_C + slot] = pk;
      else ebuf[atomicAdd(&gcur[b], 1)] = pk;   // rare overflow
    }
    __syncthreads();
    for (int b = t; b < nb; b += 256) {
      int c = min(cnt[b], STAGE_C);
      if (c >= 12) {
        int base = atomicAdd(&gcur[b], c);
        for (int k = 0; k < c; k++) ebuf[base + k] = stage[b * STAGE_C + k];
        cnt[b] = 0;
      } else if (cnt[b] > STAGE_C) {
        cnt[b] = STAGE_C;
      }
    }
    __syncthreads();
  }
  // final flush
  for (int b = t; b < nb; b += 256) {
    int c = min(cnt[b], STAGE_C);
    if (c > 0) {
      int base = atomicAdd(&gcur[b], c);
      for (int k = 0; k < c; k++) ebuf[base + k] = stage[b * STAGE_C + k];
    }
  }
}

// ---- per-bucket finalize: degree, scan, row_ptr, dinv, col scatter ---------

__global__ __launch_bounds__(256) void k_finalize(const long long* __restrict__ ebuf,
    const int* __restrict__ ebase, const int* __restrict__ cbase, int n, int nb,
    int* __restrict__ row_ptr, float* __restrict__ dinv, int* __restrict__ col) {
  __shared__ int ldeg[BW];
  __shared__ int lofs[BW];
  __shared__ int lcur[BW];
  __shared__ int wsum[256];
  const int b = blockIdx.x;
  const int t = threadIdx.x;
  const int lo = b * BW;
  const int nn = min(BW, n - lo);
  const int eb = ebase[b], ee = ebase[b + 1];
  const int cb = cbase[b];
  for (int k = t; k < BW; k += 256) ldeg[k] = 0;
  __syncthreads();
  for (int k = t; k < nn; k += 256) ldeg[k] = 1;  // self-loop
  __syncthreads();
  for (int j = eb + t; j < ee; j += 256) {
    int d = (int)(ebuf[j] >> 32);
    atomicAdd(&ldeg[d - lo], 1);
  }
  __syncthreads();
  // pairwise + block scan
  int p0 = ldeg[2 * t], p1 = ldeg[2 * t + 1];
  wsum[t] = p0 + p1;
  __syncthreads();
  for (int off = 1; off < 256; off <<= 1) {
    int v = (t >= off) ? wsum[t - off] : 0;
    __syncthreads();
    wsum[t] += v;
    __syncthreads();
  }
  int pb = (t == 0) ? 0 : wsum[t - 1];
  lofs[2 * t] = pb;
  lofs[2 * t + 1] = pb + p0;
  __syncthreads();
  for (int k = t; k < nn; k += 256) {
    int base = cb + lofs[k];
    row_ptr[lo + k] = base;
    dinv[lo + k] = rsqrtf((float)ldeg[k]);
    col[base] = lo + k;          // self-loop entry
    lcur[k] = lofs[k] + 1;
  }
  if (b == nb - 1 && t == 0) row_ptr[n] = cbase[nb];
  __syncthreads();
  for (int j = eb + t; j < ee; j += 256) {
    long long pk = ebuf[j];
    int s = (int)(pk & 0xffffffffLL);
    int d = (int)(pk >> 32);
    int p = atomicAdd(&lcur[d - lo], 1);
    col[cb + p] = s;
  }
}

// ---- feature prescale -----------------------------------------------------

__global__ void k_scale(const float* __restrict__ x, const float* __restrict__ dinv,
                        float* __restrict__ xs, int total) {
  int i = blockIdx.x * blockDim.x + threadIdx.x;
  if (i < total) xs[i] = x[i] * dinv[i >> 6];
}

// ---- aggregation: wave per node, 4 edges x 16 float4-lanes ----------------

template<bool BIAS>
__global__ __launch_bounds__(256) void k_agg(const float* __restrict__ feat,
    const int* __restrict__ row_ptr, const int* __restrict__ col,
    const float* __restrict__ dinv, const float* __restrict__ bias,
    float* __restrict__ out, int n) {
  const int wid = threadIdx.x >> 6;
  const int lane = threadIdx.x & 63;
  const int es = lane >> 4;      // edge sub-slot 0..3
  const int c4 = lane & 15;      // float4 channel group
  const int d = blockIdx.x * 4 + wid;
  if (d >= n) return;
  const int beg = row_ptr[d], end = row_ptr[d + 1];
  const float4* f4 = (const float4*)feat;
  float4 acc = make_float4(0.f, 0.f, 0.f, 0.f);
  for (int j = beg + es; j < end; j += 4) {
    int s = col[j];
    float4 v = f4[(size_t)s * 16 + c4];
    acc.x += v.x; acc.y += v.y; acc.z += v.z; acc.w += v.w;
  }
#pragma unroll
  for (int off = 16; off <= 32; off <<= 1) {
    acc.x += __shfl_xor(acc.x, off);
    acc.y += __shfl_xor(acc.y, off);
    acc.z += __shfl_xor(acc.z, off);
    acc.w += __shfl_xor(acc.w, off);
  }
  if (es == 0) {
    float sc = dinv[d];
    acc.x *= sc; acc.y *= sc; acc.z *= sc; acc.w *= sc;
    if (BIAS) {
      float4 bb = ((const float4*)bias)[c4];
      acc.x += bb.x; acc.y += bb.y; acc.z += bb.z; acc.w += bb.w;
    }
    ((float4*)out)[(size_t)d * 16 + c4] = acc;
  }
}

// ---- fp32 GEMM: [M,K] @ [K,N], W staged in LDS, 4ch x NT-node reg tile ----
// MODE 1: out = relu(acc + bias[c]) * dinv[row]; MODE 2: out = acc

template<int K, int N, int MODE>
__global__ __launch_bounds__(256) void k_gemm(const float* __restrict__ A,
    const float* __restrict__ W, const float* __restrict__ bias,
    const float* __restrict__ dinv, float* __restrict__ out, int M) {
  constexpr int TILE_M = 32;
  constexpr int TILE_K = 64;
  constexpr int XS = TILE_K + 4;
  constexpr int CG = N / 4;
  constexpr int NG = 256 / CG;
  constexpr int NT = TILE_M / NG;
  __shared__ float sW[K * N];
  __shared__ float sX[TILE_M * XS];
  const int t = threadIdx.x;
  for (int i = t; i < K * N / 4; i += 256)
    ((float4*)sW)[i] = ((const float4*)W)[i];
  const int m0 = blockIdx.x * TILE_M;
  const int cg = t % CG, ng = t / CG;
  const int c0 = cg * 4;
  float4 acc[NT];
#pragma unroll
  for (int i = 0; i < NT; i++) acc[i] = make_float4(0.f, 0.f, 0.f, 0.f);
  for (int kt = 0; kt < K; kt += TILE_K) {
    __syncthreads();
    for (int i = t; i < TILE_M * TILE_K / 4; i += 256) {
      int r = i >> 4, q = i & 15;
      int row = m0 + r;
      row = row < M ? row : M - 1;
      *(float4*)&sX[r * XS + q * 4] = *(const float4*)&A[(size_t)row * K + kt + q * 4];
    }
    __syncthreads();
#pragma unroll 4
    for (int k = 0; k < TILE_K; k += 4) {
      float4 w0 = *(float4*)&sW[(kt + k + 0) * N + c0];
      float4 w1 = *(float4*)&sW[(kt + k + 1) * N + c0];
      float4 w2 = *(float4*)&sW[(kt + k + 2) * N + c0];
      float4 w3 = *(float4*)&sW[(kt + k + 3) * N + c0];
#pragma unroll
      for (int i = 0; i < NT; i++) {
        float4 xq = *(float4*)&sX[(ng * NT + i) * XS + k];
        acc[i].x += xq.x * w0.x + xq.y * w1.x + xq.z * w2.x + xq.w * w3.x;
        acc[i].y += xq.x * w0.y + xq.y * w1.y + xq.z * w2.y + xq.w * w3.y;
        acc[i].z += xq.x * w0.z + xq.y * w1.z + xq.z * w2.z + xq.w * w3.z;
        acc[i].w += xq.x * w0.w + xq.y * w1.w + xq.z * w2.w + xq.w * w3.w;
      }
    }
  }
#pragma unroll
  for (int i = 0; i < NT; i++) {
    int nrow = m0 + ng * NT + i;
    if (nrow >= M) continue;
    float4 r = acc[i];
    if (MODE == 1) {
      float s = dinv[nrow];
      r.x = fmaxf(r.x + bias[c0 + 0], 0.f) * s;
      r.y = fmaxf(r.y + bias[c0 + 1], 0.f) * s;
      r.z = fmaxf(r.z + bias[c0 + 2], 0.f) * s;
      r.w = fmaxf(r.w + bias[c0 + 3], 0.f) * s;
    }
    *(float4*)&out[(size_t)nrow * N + c0] = r;
  }
}

// ---- launch ---------------------------------------------------------------

extern "C" void kernel_launch(void* const* d_in, const int* in_sizes, int n_in,
                              void* d_out, int out_size, void* d_ws, size_t ws_size,
                              hipStream_t stream) {
  const float* x  = (const float*)d_in[0];
  const int*   ei = (const int*)d_in[1];
  const float* W1 = (const float*)d_in[2];
  const float* b1 = (const float*)d_in[3];
  const float* W2 = (const float*)d_in[4];
  const float* b2 = (const float*)d_in[5];
  float* out = (float*)d_out;

  const int n = in_sizes[0] / IN_C;   // 100000
  const int e = in_sizes[1] / 2;      // 3200000
  const int nb = (n + BW - 1) >> BSHIFT;  // 196

  char* p = (char*)d_ws;
  auto alloc = [&](size_t bytes) {
    char* r = p;
    p += (bytes + 255) & ~(size_t)255;
    return r;
  };
  int*   flag       = (int*)alloc(4);
  int*   bucket_cnt = (int*)alloc((size_t)nb * 4);
  int*   ebase      = (int*)alloc((size_t)(nb + 1) * 4);
  int*   cbase      = (int*)alloc((size_t)(nb + 1) * 4);
  int*   gcur       = (int*)alloc((size_t)nb * 4);
  int*   row_ptr    = (int*)alloc((size_t)(n + 1) * 4);
  float* dinv       = (float*)alloc((size_t)n * 4);
  int*   col        = (int*)alloc((size_t)(e + n) * 4);
  float* xs         = (float*)alloc((size_t)n * IN_C * 4);
  float* A1         = (float*)alloc((size_t)n * IN_C * 4);
  float* a1s        = (float*)alloc((size_t)n * HID_C * 4);
  float* h2s        = xs;                  // xs dead after Agg1
  long long* ebuf   = (long long*)a1s;     // a1s live only after k_finalize

  // CSR build (bucketed)
  k_detect_i64<<<1, 256, 0, stream>>>(ei, e, flag);
  k_zero<<<(nb + 255) / 256, 256, 0, stream>>>(bucket_cnt, nb);
  k_bhist<<<1024, 256, nb * 4, stream>>>(ei, e, n, nb, bucket_cnt, flag);
  k_bscan<<<1, 256, 0, stream>>>(bucket_cnt, nb, n, ebase, cbase, gcur);
  size_t blds = ((nb + 1) & ~1) * 4 + (size_t)nb * STAGE_C * 8;
  k_bucket<<<1024, 256, blds, stream>>>(ei, e, n, nb, gcur, ebuf, flag);
  k_finalize<<<nb, 256, 0, stream>>>(ebuf, ebase, cbase, n, nb, row_ptr, dinv, col);

  // Layer 1: prescale x, aggregate (64ch), GEMM 64->128 (+b1, relu, *dinv)
  k_scale<<<((size_t)n * IN_C + 255) / 256, 256, 0, stream>>>(x, dinv, xs, n * IN_C);
  k_agg<false><<<(n + 3) / 4, 256, 0, stream>>>(xs, row_ptr, col, dinv, nullptr, A1, n);
  k_gemm<IN_C, HID_C, 1><<<(n + 31) / 32, 256, 0, stream>>>(A1, W1, b1, dinv, a1s, n);

  // Layer 2: GEMM 128->64 (plain), aggregate (64ch, *dinv[d], +b2) -> out
  k_gemm<HID_C, OUT_C, 2><<<(n + 31) / 32, 256, 0, stream>>>(a1s, W2, nullptr, dinv, h2s, n);
  k_agg<true><<<(n + 3) / 4, 256, 0, stream>>>(h2s, row_ptr, col, dinv, b2, out, n);
}

// Round 4
// 635.122 us; speedup vs baseline: 1.9460x; 1.0082x over previous
//
#include <hip/hip_runtime.h>
#include <math.h>

// GCN 2-layer: N=100K nodes, E=3.2M edges (+N self loops), 64 -> 128 -> 64.
//  - Fold norm: out[d] = dinv[d] * sum_s (dinv[s]*h[s]) + b
//  - Layer 1: aggregate x first (64ch) then GEMM; layer 2: GEMM then aggregate.
//  - CSR build via two-pass radix partition into 512-node buckets:
//    R2: flat atomic scatter = 15x write amplification (294 us).
//    R3: LDS-staged bucket scatter = flush serialization (157 us, VALU 3%).
//    R4: per-block offsets precomputed (k_part1+k_pscan), direct writes in
//    k_part2 — no global atomics, no staging, full thread parallelism.

#define IN_C 64
#define HID_C 128
#define OUT_C 64
#define BSHIFT 9
#define BW (1 << BSHIFT)          // 512 nodes per bucket
#define NPB 1024                  // partition blocks

// ---- int64/int32 edge layout detection ------------------------------------

__global__ void k_detect_i64(const int* __restrict__ ei, int e, int* __restrict__ flag) {
  __shared__ int any;
  if (threadIdx.x == 0) any = 0;
  __syncthreads();
  int lim = min(e, 2048);
  int found = 0;
  for (int i = threadIdx.x; i < lim; i += 256)
    if (ei[2 * i + 1] != 0) found = 1;
  if (found) atomicOr(&any, 1);
  __syncthreads();
  if (threadIdx.x == 0) *flag = any;  // 1 => int32 layout, 0 => int64 layout
}

// ---- pass 1: per-block bucket histogram ------------------------------------

__global__ __launch_bounds__(256) void k_part1(const int* __restrict__ ei, int e, int n,
    int nb, int* __restrict__ pcnt, const int* __restrict__ flag) {
  extern __shared__ int lh[];
  const int t = threadIdx.x;
  for (int i = t; i < nb; i += 256) lh[i] = 0;
  __syncthreads();
  const int f = *flag;
  const int chunk = (e + NPB - 1) / NPB;
  const int lo = blockIdx.x * chunk;
  const int hi = min(lo + chunk, e);
  for (int i = lo + t; i < hi; i += 256) {
    int d = f ? ei[e + i] : (int)(((const long long*)ei)[e + i]);
    d = min(max(d, 0), n - 1);
    atomicAdd(&lh[d >> BSHIFT], 1);
  }
  __syncthreads();
  for (int i = t; i < nb; i += 256) pcnt[blockIdx.x * nb + i] = lh[i];
}

// ---- scan: pcnt -> per-block exclusive offsets; bucket totals -> bases -----

__global__ __launch_bounds__(256) void k_pscan(int* __restrict__ pcnt,
    int nb, int n, int* __restrict__ ebase, int* __restrict__ cbase) {
  __shared__ int se[256], sc[256];
  const int t = threadIdx.x;
  int total = 0, nodes = 0;
  if (t < nb) {
    for (int b = 0; b < NPB; b++) {
      int c = pcnt[b * nb + t];
      pcnt[b * nb + t] = total;
      total += c;
    }
    nodes = min(BW, n - t * BW);
  }
  se[t] = total; sc[t] = total + nodes;
  __syncthreads();
  for (int off = 1; off < 256; off <<= 1) {
    int ve = (t >= off) ? se[t - off] : 0;
    int vc = (t >= off) ? sc[t - off] : 0;
    __syncthreads();
    se[t] += ve; sc[t] += vc;
    __syncthreads();
  }
  if (t < nb) {
    ebase[t + 1] = se[t];
    cbase[t + 1] = sc[t];
    if (t == 0) { ebase[0] = 0; cbase[0] = 0; }
  }
}

// ---- pass 2: direct partitioned scatter (block-private regions) ------------

__global__ __launch_bounds__(256) void k_part2(const int* __restrict__ ei, int e, int n,
    int nb, const int* __restrict__ pcnt, const int* __restrict__ ebase,
    long long* __restrict__ ebuf, const int* __restrict__ flag) {
  extern __shared__ int lds2[];
  int* base_l = lds2;       // nb
  int* cur    = lds2 + nb;  // nb
  const int t = threadIdx.x;
  for (int i = t; i < nb; i += 256) {
    base_l[i] = ebase[i] + pcnt[blockIdx.x * nb + i];
    cur[i] = 0;
  }
  __syncthreads();
  const int f = *flag;
  const int chunk = (e + NPB - 1) / NPB;
  const int lo = blockIdx.x * chunk;
  const int hi = min(lo + chunk, e);
  for (int i = lo + t; i < hi; i += 256) {
    int s, d;
    if (f) { s = ei[i]; d = ei[e + i]; }
    else {
      s = (int)(((const long long*)ei)[i]);
      d = (int)(((const long long*)ei)[e + i]);
    }
    s = min(max(s, 0), n - 1);
    d = min(max(d, 0), n - 1);
    int b = d >> BSHIFT;
    int slot = atomicAdd(&cur[b], 1);
    ebuf[base_l[b] + slot] = ((long long)d << 32) | (unsigned)s;
  }
}

// ---- per-bucket finalize: degree, scan, row_ptr, dinv, col scatter ---------

__global__ __launch_bounds__(256) void k_finalize(const long long* __restrict__ ebuf,
    const int* __restrict__ ebase, const int* __restrict__ cbase, int n, int nb,
    int* __restrict__ row_ptr, float* __restrict__ dinv, int* __restrict__ col) {
  __shared__ int ldeg[BW];
  __shared__ int lofs[BW];
  __shared__ int lcur[BW];
  __shared__ int wsum[256];
  const int b = blockIdx.x;
  const int t = threadIdx.x;
  const int lo = b * BW;
  const int nn = min(BW, n - lo);
  const int eb = ebase[b], ee = ebase[b + 1];
  const int cb = cbase[b];
  for (int k = t; k < BW; k += 256) ldeg[k] = 0;
  __syncthreads();
  for (int k = t; k < nn; k += 256) ldeg[k] = 1;  // self-loop
  __syncthreads();
  for (int j = eb + t; j < ee; j += 256) {
    int d = (int)(ebuf[j] >> 32);
    atomicAdd(&ldeg[d - lo], 1);
  }
  __syncthreads();
  int p0 = ldeg[2 * t], p1 = ldeg[2 * t + 1];
  wsum[t] = p0 + p1;
  __syncthreads();
  for (int off = 1; off < 256; off <<= 1) {
    int v = (t >= off) ? wsum[t - off] : 0;
    __syncthreads();
    wsum[t] += v;
    __syncthreads();
  }
  int pb = (t == 0) ? 0 : wsum[t - 1];
  lofs[2 * t] = pb;
  lofs[2 * t + 1] = pb + p0;
  __syncthreads();
  for (int k = t; k < nn; k += 256) {
    int base = cb + lofs[k];
    row_ptr[lo + k] = base;
    dinv[lo + k] = rsqrtf((float)ldeg[k]);
    col[base] = lo + k;          // self-loop entry
    lcur[k] = lofs[k] + 1;
  }
  if (b == nb - 1 && t == 0) row_ptr[n] = cbase[nb];
  __syncthreads();
  for (int j = eb + t; j < ee; j += 256) {
    long long pk = ebuf[j];
    int s = (int)(pk & 0xffffffffLL);
    int d = (int)(pk >> 32);
    int p = atomicAdd(&lcur[d - lo], 1);
    col[cb + p] = s;
  }
}

// ---- feature prescale -----------------------------------------------------

__global__ void k_scale(const float* __restrict__ x, const float* __restrict__ dinv,
                        float* __restrict__ xs, int total) {
  int i = blockIdx.x * blockDim.x + threadIdx.x;
  if (i < total) xs[i] = x[i] * dinv[i >> 6];
}

// ---- aggregation: wave per node, 4 edges x 16 float4-lanes, pipelined ------

template<bool BIAS>
__global__ __launch_bounds__(256) void k_agg(const float* __restrict__ feat,
    const int* __restrict__ row_ptr, const int* __restrict__ col,
    const float* __restrict__ dinv, const float* __restrict__ bias,
    float* __restrict__ out, int n) {
  const int wid = threadIdx.x >> 6;
  const int lane = threadIdx.x & 63;
  const int es = lane >> 4;      // edge sub-slot 0..3
  const int c4 = lane & 15;      // float4 channel group
  const int d = blockIdx.x * 4 + wid;
  if (d >= n) return;
  const int beg = row_ptr[d], end = row_ptr[d + 1];
  const float4* f4 = (const float4*)feat;
  float4 acc = make_float4(0.f, 0.f, 0.f, 0.f);
  int j = beg + es;
  if (j < end) {
    int s0 = col[j];
    float4 v0 = f4[(size_t)s0 * 16 + c4];
    for (j += 4; j < end; j += 4) {
      int s1 = col[j];
      float4 v1 = f4[(size_t)s1 * 16 + c4];   // in flight while v0 consumed
      acc.x += v0.x; acc.y += v0.y; acc.z += v0.z; acc.w += v0.w;
      v0 = v1;
    }
    acc.x += v0.x; acc.y += v0.y; acc.z += v0.z; acc.w += v0.w;
  }
#pragma unroll
  for (int off = 16; off <= 32; off <<= 1) {
    acc.x += __shfl_xor(acc.x, off);
    acc.y += __shfl_xor(acc.y, off);
    acc.z += __shfl_xor(acc.z, off);
    acc.w += __shfl_xor(acc.w, off);
  }
  if (es == 0) {
    float sc = dinv[d];
    acc.x *= sc; acc.y *= sc; acc.z *= sc; acc.w *= sc;
    if (BIAS) {
      float4 bb = ((const float4*)bias)[c4];
      acc.x += bb.x; acc.y += bb.y; acc.z += bb.z; acc.w += bb.w;
    }
    ((float4*)out)[(size_t)d * 16 + c4] = acc;
  }
}

// ---- fp32 GEMM: [M,K] @ [K,N], W staged in LDS, 4ch x NT-node reg tile ----
// MODE 1: out = relu(acc + bias[c]) * dinv[row]; MODE 2: out = acc

template<int K, int N, int MODE>
__global__ __launch_bounds__(256) void k_gemm(const float* __restrict__ A,
    const float* __restrict__ W, const float* __restrict__ bias,
    const float* __restrict__ dinv, float* __restrict__ out, int M) {
  constexpr int TILE_M = 32;
  constexpr int TILE_K = 64;
  constexpr int XS = TILE_K + 4;
  constexpr int CG = N / 4;
  constexpr int NG = 256 / CG;
  constexpr int NT = TILE_M / NG;
  __shared__ float sW[K * N];
  __shared__ float sX[TILE_M * XS];
  const int t = threadIdx.x;
  for (int i = t; i < K * N / 4; i += 256)
    ((float4*)sW)[i] = ((const float4*)W)[i];
  const int m0 = blockIdx.x * TILE_M;
  const int cg = t % CG, ng = t / CG;
  const int c0 = cg * 4;
  float4 acc[NT];
#pragma unroll
  for (int i = 0; i < NT; i++) acc[i] = make_float4(0.f, 0.f, 0.f, 0.f);
  for (int kt = 0; kt < K; kt += TILE_K) {
    __syncthreads();
    for (int i = t; i < TILE_M * TILE_K / 4; i += 256) {
      int r = i >> 4, q = i & 15;
      int row = m0 + r;
      row = row < M ? row : M - 1;
      *(float4*)&sX[r * XS + q * 4] = *(const float4*)&A[(size_t)row * K + kt + q * 4];
    }
    __syncthreads();
#pragma unroll 4
    for (int k = 0; k < TILE_K; k += 4) {
      float4 w0 = *(float4*)&sW[(kt + k + 0) * N + c0];
      float4 w1 = *(float4*)&sW[(kt + k + 1) * N + c0];
      float4 w2 = *(float4*)&sW[(kt + k + 2) * N + c0];
      float4 w3 = *(float4*)&sW[(kt + k + 3) * N + c0];
#pragma unroll
      for (int i = 0; i < NT; i++) {
        float4 xq = *(float4*)&sX[(ng * NT + i) * XS + k];
        acc[i].x += xq.x * w0.x + xq.y * w1.x + xq.z * w2.x + xq.w * w3.x;
        acc[i].y += xq.x * w0.y + xq.y * w1.y + xq.z * w2.y + xq.w * w3.y;
        acc[i].z += xq.x * w0.z + xq.y * w1.z + xq.z * w2.z + xq.w * w3.z;
        acc[i].w += xq.x * w0.w + xq.y * w1.w + xq.z * w2.w + xq.w * w3.w;
      }
    }
  }
#pragma unroll
  for (int i = 0; i < NT; i++) {
    int nrow = m0 + ng * NT + i;
    if (nrow >= M) continue;
    float4 r = acc[i];
    if (MODE == 1) {
      float s = dinv[nrow];
      r.x = fmaxf(r.x + bias[c0 + 0], 0.f) * s;
      r.y = fmaxf(r.y + bias[c0 + 1], 0.f) * s;
      r.z = fmaxf(r.z + bias[c0 + 2], 0.f) * s;
      r.w = fmaxf(r.w + bias[c0 + 3], 0.f) * s;
    }
    *(float4*)&out[(size_t)nrow * N + c0] = r;
  }
}

// ---- launch ---------------------------------------------------------------

extern "C" void kernel_launch(void* const* d_in, const int* in_sizes, int n_in,
                              void* d_out, int out_size, void* d_ws, size_t ws_size,
                              hipStream_t stream) {
  const float* x  = (const float*)d_in[0];
  const int*   ei = (const int*)d_in[1];
  const float* W1 = (const float*)d_in[2];
  const float* b1 = (const float*)d_in[3];
  const float* W2 = (const float*)d_in[4];
  const float* b2 = (const float*)d_in[5];
  float* out = (float*)d_out;

  const int n = in_sizes[0] / IN_C;   // 100000
  const int e = in_sizes[1] / 2;      // 3200000
  const int nb = (n + BW - 1) >> BSHIFT;  // 196 (must be <= 256)

  char* p = (char*)d_ws;
  auto alloc = [&](size_t bytes) {
    char* r = p;
    p += (bytes + 255) & ~(size_t)255;
    return r;
  };
  int*   flag       = (int*)alloc(4);
  int*   pcnt       = (int*)alloc((size_t)NPB * nb * 4);
  int*   ebase      = (int*)alloc((size_t)(nb + 1) * 4);
  int*   cbase      = (int*)alloc((size_t)(nb + 1) * 4);
  int*   row_ptr    = (int*)alloc((size_t)(n + 1) * 4);
  float* dinv       = (float*)alloc((size_t)n * 4);
  int*   col        = (int*)alloc((size_t)(e + n) * 4);
  float* xs         = (float*)alloc((size_t)n * IN_C * 4);
  float* A1         = (float*)alloc((size_t)n * IN_C * 4);
  float* a1s        = (float*)alloc((size_t)n * HID_C * 4);
  float* h2s        = xs;                  // xs dead after Agg1
  long long* ebuf   = (long long*)a1s;     // a1s live only after k_finalize

  // CSR build (two-pass radix partition)
  k_detect_i64<<<1, 256, 0, stream>>>(ei, e, flag);
  k_part1<<<NPB, 256, nb * 4, stream>>>(ei, e, n, nb, pcnt, flag);
  k_pscan<<<1, 256, 0, stream>>>(pcnt, nb, n, ebase, cbase);
  k_part2<<<NPB, 256, 2 * nb * 4, stream>>>(ei, e, n, nb, pcnt, ebase, ebuf, flag);
  k_finalize<<<nb, 256, 0, stream>>>(ebuf, ebase, cbase, n, nb, row_ptr, dinv, col);

  // Layer 1: prescale x, aggregate (64ch), GEMM 64->128 (+b1, relu, *dinv)
  k_scale<<<((size_t)n * IN_C + 255) / 256, 256, 0, stream>>>(x, dinv, xs, n * IN_C);
  k_agg<false><<<(n + 3) / 4, 256, 0, stream>>>(xs, row_ptr, col, dinv, nullptr, A1, n);
  k_gemm<IN_C, HID_C, 1><<<(n + 31) / 32, 256, 0, stream>>>(A1, W1, b1, dinv, a1s, n);

  // Layer 2: GEMM 128->64 (plain), aggregate (64ch, *dinv[d], +b2) -> out
  k_gemm<HID_C, OUT_C, 2><<<(n + 31) / 32, 256, 0, stream>>>(a1s, W2, nullptr, dinv, h2s, n);
  k_agg<true><<<(n + 3) / 4, 256, 0, stream>>>(h2s, row_ptr, col, dinv, b2, out, n);
}

// Round 5
// 492.786 us; speedup vs baseline: 2.5081x; 1.2888x over previous
//
#include <hip/hip_runtime.h>
#include <math.h>

// GCN 2-layer: N=100K nodes, E=3.2M edges (+N self loops), 64 -> 128 -> 64.
//  - Fold norm: out[d] = dinv[d] * sum_s (dinv[s]*h[s]) + b
//  - Layer 1: aggregate x first (64ch) then GEMM; layer 2: GEMM then aggregate.
//  - CSR build via two-pass radix partition into 512-node buckets:
//    R2: flat atomic scatter = 15x write amplification (294 us).
//    R3: LDS-staged bucket scatter = flush serialization (157 us).
//    R4: single-block pscan = latency-bound serial column reads (140 us).
//    R5: pcnt transposed to [bucket][block]; parallel per-bucket scan
//    (k_bscan, 196 blocks) + tiny top-level scan (k_sscan).

#define IN_C 64
#define HID_C 128
#define OUT_C 64
#define BSHIFT 9
#define BW (1 << BSHIFT)          // 512 nodes per bucket
#define NPB 1024                  // partition blocks

// ---- int64/int32 edge layout detection ------------------------------------

__global__ void k_detect_i64(const int* __restrict__ ei, int e, int* __restrict__ flag) {
  __shared__ int any;
  if (threadIdx.x == 0) any = 0;
  __syncthreads();
  int lim = min(e, 2048);
  int found = 0;
  for (int i = threadIdx.x; i < lim; i += 256)
    if (ei[2 * i + 1] != 0) found = 1;
  if (found) atomicOr(&any, 1);
  __syncthreads();
  if (threadIdx.x == 0) *flag = any;  // 1 => int32 layout, 0 => int64 layout
}

// ---- pass 1: per-block bucket histogram (transposed store) -----------------

__global__ __launch_bounds__(256) void k_part1(const int* __restrict__ ei, int e, int n,
    int nb, int* __restrict__ pcnt, const int* __restrict__ flag) {
  extern __shared__ int lh[];
  const int t = threadIdx.x;
  for (int i = t; i < nb; i += 256) lh[i] = 0;
  __syncthreads();
  const int f = *flag;
  const int chunk = (e + NPB - 1) / NPB;
  const int lo = blockIdx.x * chunk;
  const int hi = min(lo + chunk, e);
  for (int i = lo + t; i < hi; i += 256) {
    int d = f ? ei[e + i] : (int)(((const long long*)ei)[e + i]);
    d = min(max(d, 0), n - 1);
    atomicAdd(&lh[d >> BSHIFT], 1);
  }
  __syncthreads();
  for (int i = t; i < nb; i += 256) pcnt[(size_t)i * NPB + blockIdx.x] = lh[i];
}

// ---- per-bucket parallel scan over NPB block-counts ------------------------

__global__ __launch_bounds__(256) void k_bscan(int* __restrict__ pcnt,
    int* __restrict__ btot) {
  __shared__ int ws[256];
  const int b = blockIdx.x;
  const int t = threadIdx.x;
  int* row = pcnt + (size_t)b * NPB;
  int4 v = ((int4*)row)[t];             // 4 counts per thread
  int s0 = v.x;
  int s1 = s0 + v.y;
  int s2 = s1 + v.z;
  int s3 = s2 + v.w;
  ws[t] = s3;
  __syncthreads();
  for (int off = 1; off < 256; off <<= 1) {
    int u = (t >= off) ? ws[t - off] : 0;
    __syncthreads();
    ws[t] += u;
    __syncthreads();
  }
  int base = (t == 0) ? 0 : ws[t - 1];
  ((int4*)row)[t] = make_int4(base, base + s0, base + s1, base + s2);
  if (t == 255) btot[b] = ws[255];
}

// ---- top-level scan: bucket totals -> ebase/cbase --------------------------

__global__ __launch_bounds__(256) void k_sscan(const int* __restrict__ btot,
    int nb, int n, int* __restrict__ ebase, int* __restrict__ cbase) {
  __shared__ int se[256], sc[256];
  const int t = threadIdx.x;
  int total = 0, nodes = 0;
  if (t < nb) {
    total = btot[t];
    nodes = min(BW, n - t * BW);
  }
  se[t] = total; sc[t] = total + nodes;
  __syncthreads();
  for (int off = 1; off < 256; off <<= 1) {
    int ve = (t >= off) ? se[t - off] : 0;
    int vc = (t >= off) ? sc[t - off] : 0;
    __syncthreads();
    se[t] += ve; sc[t] += vc;
    __syncthreads();
  }
  if (t < nb) {
    ebase[t + 1] = se[t];
    cbase[t + 1] = sc[t];
    if (t == 0) { ebase[0] = 0; cbase[0] = 0; }
  }
}

// ---- pass 2: direct partitioned scatter (block-private regions) ------------

__global__ __launch_bounds__(256) void k_part2(const int* __restrict__ ei, int e, int n,
    int nb, const int* __restrict__ pcnt, const int* __restrict__ ebase,
    long long* __restrict__ ebuf, const int* __restrict__ flag) {
  extern __shared__ int lds2[];
  int* base_l = lds2;       // nb
  int* cur    = lds2 + nb;  // nb
  const int t = threadIdx.x;
  for (int i = t; i < nb; i += 256) {
    base_l[i] = ebase[i] + pcnt[(size_t)i * NPB + blockIdx.x];
    cur[i] = 0;
  }
  __syncthreads();
  const int f = *flag;
  const int chunk = (e + NPB - 1) / NPB;
  const int lo = blockIdx.x * chunk;
  const int hi = min(lo + chunk, e);
  for (int i = lo + t; i < hi; i += 256) {
    int s, d;
    if (f) { s = ei[i]; d = ei[e + i]; }
    else {
      s = (int)(((const long long*)ei)[i]);
      d = (int)(((const long long*)ei)[e + i]);
    }
    s = min(max(s, 0), n - 1);
    d = min(max(d, 0), n - 1);
    int b = d >> BSHIFT;
    int slot = atomicAdd(&cur[b], 1);
    ebuf[base_l[b] + slot] = ((long long)d << 32) | (unsigned)s;
  }
}

// ---- per-bucket finalize: degree, scan, row_ptr, dinv, col scatter ---------

__global__ __launch_bounds__(256) void k_finalize(const long long* __restrict__ ebuf,
    const int* __restrict__ ebase, const int* __restrict__ cbase, int n, int nb,
    int* __restrict__ row_ptr, float* __restrict__ dinv, int* __restrict__ col) {
  __shared__ int ldeg[BW];
  __shared__ int lofs[BW];
  __shared__ int lcur[BW];
  __shared__ int wsum[256];
  const int b = blockIdx.x;
  const int t = threadIdx.x;
  const int lo = b * BW;
  const int nn = min(BW, n - lo);
  const int eb = ebase[b], ee = ebase[b + 1];
  const int cb = cbase[b];
  for (int k = t; k < BW; k += 256) ldeg[k] = 0;
  __syncthreads();
  for (int k = t; k < nn; k += 256) ldeg[k] = 1;  // self-loop
  __syncthreads();
  for (int j = eb + t; j < ee; j += 256) {
    int d = (int)(ebuf[j] >> 32);
    atomicAdd(&ldeg[d - lo], 1);
  }
  __syncthreads();
  int p0 = ldeg[2 * t], p1 = ldeg[2 * t + 1];
  wsum[t] = p0 + p1;
  __syncthreads();
  for (int off = 1; off < 256; off <<= 1) {
    int v = (t >= off) ? wsum[t - off] : 0;
    __syncthreads();
    wsum[t] += v;
    __syncthreads();
  }
  int pb = (t == 0) ? 0 : wsum[t - 1];
  lofs[2 * t] = pb;
  lofs[2 * t + 1] = pb + p0;
  __syncthreads();
  for (int k = t; k < nn; k += 256) {
    int base = cb + lofs[k];
    row_ptr[lo + k] = base;
    dinv[lo + k] = rsqrtf((float)ldeg[k]);
    col[base] = lo + k;          // self-loop entry
    lcur[k] = lofs[k] + 1;
  }
  if (b == nb - 1 && t == 0) row_ptr[n] = cbase[nb];
  __syncthreads();
  for (int j = eb + t; j < ee; j += 256) {
    long long pk = ebuf[j];
    int s = (int)(pk & 0xffffffffLL);
    int d = (int)(pk >> 32);
    int p = atomicAdd(&lcur[d - lo], 1);
    col[cb + p] = s;
  }
}

// ---- feature prescale -----------------------------------------------------

__global__ void k_scale(const float* __restrict__ x, const float* __restrict__ dinv,
                        float* __restrict__ xs, int total) {
  int i = blockIdx.x * blockDim.x + threadIdx.x;
  if (i < total) xs[i] = x[i] * dinv[i >> 6];
}

// ---- aggregation: wave per node, 4 edges x 16 float4-lanes, pipelined ------

template<bool BIAS>
__global__ __launch_bounds__(256) void k_agg(const float* __restrict__ feat,
    const int* __restrict__ row_ptr, const int* __restrict__ col,
    const float* __restrict__ dinv, const float* __restrict__ bias,
    float* __restrict__ out, int n) {
  const int wid = threadIdx.x >> 6;
  const int lane = threadIdx.x & 63;
  const int es = lane >> 4;      // edge sub-slot 0..3
  const int c4 = lane & 15;      // float4 channel group
  const int d = blockIdx.x * 4 + wid;
  if (d >= n) return;
  const int beg = row_ptr[d], end = row_ptr[d + 1];
  const float4* f4 = (const float4*)feat;
  float4 acc = make_float4(0.f, 0.f, 0.f, 0.f);
  int j = beg + es;
  if (j < end) {
    int s0 = col[j];
    float4 v0 = f4[(size_t)s0 * 16 + c4];
    for (j += 4; j < end; j += 4) {
      int s1 = col[j];
      float4 v1 = f4[(size_t)s1 * 16 + c4];   // in flight while v0 consumed
      acc.x += v0.x; acc.y += v0.y; acc.z += v0.z; acc.w += v0.w;
      v0 = v1;
    }
    acc.x += v0.x; acc.y += v0.y; acc.z += v0.z; acc.w += v0.w;
  }
#pragma unroll
  for (int off = 16; off <= 32; off <<= 1) {
    acc.x += __shfl_xor(acc.x, off);
    acc.y += __shfl_xor(acc.y, off);
    acc.z += __shfl_xor(acc.z, off);
    acc.w += __shfl_xor(acc.w, off);
  }
  if (es == 0) {
    float sc = dinv[d];
    acc.x *= sc; acc.y *= sc; acc.z *= sc; acc.w *= sc;
    if (BIAS) {
      float4 bb = ((const float4*)bias)[c4];
      acc.x += bb.x; acc.y += bb.y; acc.z += bb.z; acc.w += bb.w;
    }
    ((float4*)out)[(size_t)d * 16 + c4] = acc;
  }
}

// ---- fp32 GEMM: [M,K] @ [K,N], W staged in LDS, 4ch x NT-node reg tile ----
// MODE 1: out = relu(acc + bias[c]) * dinv[row]; MODE 2: out = acc

template<int K, int N, int MODE>
__global__ __launch_bounds__(256) void k_gemm(const float* __restrict__ A,
    const float* __restrict__ W, const float* __restrict__ bias,
    const float* __restrict__ dinv, float* __restrict__ out, int M) {
  constexpr int TILE_M = 32;
  constexpr int TILE_K = 64;
  constexpr int XS = TILE_K + 4;
  constexpr int CG = N / 4;
  constexpr int NG = 256 / CG;
  constexpr int NT = TILE_M / NG;
  __shared__ float sW[K * N];
  __shared__ float sX[TILE_M * XS];
  const int t = threadIdx.x;
  for (int i = t; i < K * N / 4; i += 256)
    ((float4*)sW)[i] = ((const float4*)W)[i];
  const int m0 = blockIdx.x * TILE_M;
  const int cg = t % CG, ng = t / CG;
  const int c0 = cg * 4;
  float4 acc[NT];
#pragma unroll
  for (int i = 0; i < NT; i++) acc[i] = make_float4(0.f, 0.f, 0.f, 0.f);
  for (int kt = 0; kt < K; kt += TILE_K) {
    __syncthreads();
    for (int i = t; i < TILE_M * TILE_K / 4; i += 256) {
      int r = i >> 4, q = i & 15;
      int row = m0 + r;
      row = row < M ? row : M - 1;
      *(float4*)&sX[r * XS + q * 4] = *(const float4*)&A[(size_t)row * K + kt + q * 4];
    }
    __syncthreads();
#pragma unroll 4
    for (int k = 0; k < TILE_K; k += 4) {
      float4 w0 = *(float4*)&sW[(kt + k + 0) * N + c0];
      float4 w1 = *(float4*)&sW[(kt + k + 1) * N + c0];
      float4 w2 = *(float4*)&sW[(kt + k + 2) * N + c0];
      float4 w3 = *(float4*)&sW[(kt + k + 3) * N + c0];
#pragma unroll
      for (int i = 0; i < NT; i++) {
        float4 xq = *(float4*)&sX[(ng * NT + i) * XS + k];
        acc[i].x += xq.x * w0.x + xq.y * w1.x + xq.z * w2.x + xq.w * w3.x;
        acc[i].y += xq.x * w0.y + xq.y * w1.y + xq.z * w2.y + xq.w * w3.y;
        acc[i].z += xq.x * w0.z + xq.y * w1.z + xq.z * w2.z + xq.w * w3.z;
        acc[i].w += xq.x * w0.w + xq.y * w1.w + xq.z * w2.w + xq.w * w3.w;
      }
    }
  }
#pragma unroll
  for (int i = 0; i < NT; i++) {
    int nrow = m0 + ng * NT + i;
    if (nrow >= M) continue;
    float4 r = acc[i];
    if (MODE == 1) {
      float s = dinv[nrow];
      r.x = fmaxf(r.x + bias[c0 + 0], 0.f) * s;
      r.y = fmaxf(r.y + bias[c0 + 1], 0.f) * s;
      r.z = fmaxf(r.z + bias[c0 + 2], 0.f) * s;
      r.w = fmaxf(r.w + bias[c0 + 3], 0.f) * s;
    }
    *(float4*)&out[(size_t)nrow * N + c0] = r;
  }
}

// ---- launch ---------------------------------------------------------------

extern "C" void kernel_launch(void* const* d_in, const int* in_sizes, int n_in,
                              void* d_out, int out_size, void* d_ws, size_t ws_size,
                              hipStream_t stream) {
  const float* x  = (const float*)d_in[0];
  const int*   ei = (const int*)d_in[1];
  const float* W1 = (const float*)d_in[2];
  const float* b1 = (const float*)d_in[3];
  const float* W2 = (const float*)d_in[4];
  const float* b2 = (const float*)d_in[5];
  float* out = (float*)d_out;

  const int n = in_sizes[0] / IN_C;   // 100000
  const int e = in_sizes[1] / 2;      // 3200000
  const int nb = (n + BW - 1) >> BSHIFT;  // 196 (must be <= 256)

  char* p = (char*)d_ws;
  auto alloc = [&](size_t bytes) {
    char* r = p;
    p += (bytes + 255) & ~(size_t)255;
    return r;
  };
  int*   flag       = (int*)alloc(4);
  int*   pcnt       = (int*)alloc((size_t)nb * NPB * 4);
  int*   btot       = (int*)alloc((size_t)nb * 4);
  int*   ebase      = (int*)alloc((size_t)(nb + 1) * 4);
  int*   cbase      = (int*)alloc((size_t)(nb + 1) * 4);
  int*   row_ptr    = (int*)alloc((size_t)(n + 1) * 4);
  float* dinv       = (float*)alloc((size_t)n * 4);
  int*   col        = (int*)alloc((size_t)(e + n) * 4);
  float* xs         = (float*)alloc((size_t)n * IN_C * 4);
  float* A1         = (float*)alloc((size_t)n * IN_C * 4);
  float* a1s        = (float*)alloc((size_t)n * HID_C * 4);
  float* h2s        = xs;                  // xs dead after Agg1
  long long* ebuf   = (long long*)a1s;     // a1s live only after k_finalize

  // CSR build (two-pass radix partition, hierarchical scan)
  k_detect_i64<<<1, 256, 0, stream>>>(ei, e, flag);
  k_part1<<<NPB, 256, nb * 4, stream>>>(ei, e, n, nb, pcnt, flag);
  k_bscan<<<nb, 256, 0, stream>>>(pcnt, btot);
  k_sscan<<<1, 256, 0, stream>>>(btot, nb, n, ebase, cbase);
  k_part2<<<NPB, 256, 2 * nb * 4, stream>>>(ei, e, n, nb, pcnt, ebase, ebuf, flag);
  k_finalize<<<nb, 256, 0, stream>>>(ebuf, ebase, cbase, n, nb, row_ptr, dinv, col);

  // Layer 1: prescale x, aggregate (64ch), GEMM 64->128 (+b1, relu, *dinv)
  k_scale<<<((size_t)n * IN_C + 255) / 256, 256, 0, stream>>>(x, dinv, xs, n * IN_C);
  k_agg<false><<<(n + 3) / 4, 256, 0, stream>>>(xs, row_ptr, col, dinv, nullptr, A1, n);
  k_gemm<IN_C, HID_C, 1><<<(n + 31) / 32, 256, 0, stream>>>(A1, W1, b1, dinv, a1s, n);

  // Layer 2: GEMM 128->64 (plain), aggregate (64ch, *dinv[d], +b2) -> out
  k_gemm<HID_C, OUT_C, 2><<<(n + 31) / 32, 256, 0, stream>>>(a1s, W2, nullptr, dinv, h2s, n);
  k_agg<true><<<(n + 3) / 4, 256, 0, stream>>>(h2s, row_ptr, col, dinv, b2, out, n);
}

// Round 6
// 401.018 us; speedup vs baseline: 3.0821x; 1.2288x over previous
//
#include <hip/hip_runtime.h>
#include <math.h>

// GCN 2-layer: N=100K nodes, E=3.2M edges (+N self loops), 64 -> 128 -> 64.
//  - Fold norm: out[d] = dinv[d] * sum_s (dinv[s]*h[s]) + b
//  - Layer 1: aggregate x first (64ch) then GEMM; layer 2: GEMM then aggregate.
//  - R5 profile: k_agg is an L2/fabric-BW-bound random gather (845 MB req,
//    362 MB FETCH, 47% HBM). R6: gather tables in bf16 (fp32 accum) — halves
//    bytes/edge; ebuf packed to u32 (d_local:9 | src:23).

#define IN_C 64
#define HID_C 128
#define OUT_C 64
#define BSHIFT 9
#define BW (1 << BSHIFT)          // 512 nodes per bucket
#define NPB 1024                  // partition blocks

__device__ __forceinline__ float bf2f(unsigned short u) {
  return __uint_as_float((unsigned)u << 16);
}
__device__ __forceinline__ unsigned short f2bf(float f) {
  unsigned u = __float_as_uint(f);
  return (unsigned short)((u + 0x7FFF + ((u >> 16) & 1)) >> 16);  // RNE
}

// ---- int64/int32 edge layout detection ------------------------------------

__global__ void k_detect_i64(const int* __restrict__ ei, int e, int* __restrict__ flag) {
  __shared__ int any;
  if (threadIdx.x == 0) any = 0;
  __syncthreads();
  int lim = min(e, 2048);
  int found = 0;
  for (int i = threadIdx.x; i < lim; i += 256)
    if (ei[2 * i + 1] != 0) found = 1;
  if (found) atomicOr(&any, 1);
  __syncthreads();
  if (threadIdx.x == 0) *flag = any;  // 1 => int32 layout, 0 => int64 layout
}

// ---- pass 1: per-block bucket histogram (transposed store) -----------------

__global__ __launch_bounds__(256) void k_part1(const int* __restrict__ ei, int e, int n,
    int nb, int* __restrict__ pcnt, const int* __restrict__ flag) {
  extern __shared__ int lh[];
  const int t = threadIdx.x;
  for (int i = t; i < nb; i += 256) lh[i] = 0;
  __syncthreads();
  const int f = *flag;
  const int chunk = (e + NPB - 1) / NPB;
  const int lo = blockIdx.x * chunk;
  const int hi = min(lo + chunk, e);
  for (int i = lo + t; i < hi; i += 256) {
    int d = f ? ei[e + i] : (int)(((const long long*)ei)[e + i]);
    d = min(max(d, 0), n - 1);
    atomicAdd(&lh[d >> BSHIFT], 1);
  }
  __syncthreads();
  for (int i = t; i < nb; i += 256) pcnt[(size_t)i * NPB + blockIdx.x] = lh[i];
}

// ---- per-bucket parallel scan over NPB block-counts ------------------------

__global__ __launch_bounds__(256) void k_bscan(int* __restrict__ pcnt,
    int* __restrict__ btot) {
  __shared__ int ws[256];
  const int b = blockIdx.x;
  const int t = threadIdx.x;
  int* row = pcnt + (size_t)b * NPB;
  int4 v = ((int4*)row)[t];
  int s0 = v.x;
  int s1 = s0 + v.y;
  int s2 = s1 + v.z;
  int s3 = s2 + v.w;
  ws[t] = s3;
  __syncthreads();
  for (int off = 1; off < 256; off <<= 1) {
    int u = (t >= off) ? ws[t - off] : 0;
    __syncthreads();
    ws[t] += u;
    __syncthreads();
  }
  int base = (t == 0) ? 0 : ws[t - 1];
  ((int4*)row)[t] = make_int4(base, base + s0, base + s1, base + s2);
  if (t == 255) btot[b] = ws[255];
}

// ---- top-level scan: bucket totals -> ebase/cbase --------------------------

__global__ __launch_bounds__(256) void k_sscan(const int* __restrict__ btot,
    int nb, int n, int* __restrict__ ebase, int* __restrict__ cbase) {
  __shared__ int se[256], sc[256];
  const int t = threadIdx.x;
  int total = 0, nodes = 0;
  if (t < nb) {
    total = btot[t];
    nodes = min(BW, n - t * BW);
  }
  se[t] = total; sc[t] = total + nodes;
  __syncthreads();
  for (int off = 1; off < 256; off <<= 1) {
    int ve = (t >= off) ? se[t - off] : 0;
    int vc = (t >= off) ? sc[t - off] : 0;
    __syncthreads();
    se[t] += ve; sc[t] += vc;
    __syncthreads();
  }
  if (t < nb) {
    ebase[t + 1] = se[t];
    cbase[t + 1] = sc[t];
    if (t == 0) { ebase[0] = 0; cbase[0] = 0; }
  }
}

// ---- pass 2: direct partitioned scatter, u32-packed (dl:9 | src:23) --------

__global__ __launch_bounds__(256) void k_part2(const int* __restrict__ ei, int e, int n,
    int nb, const int* __restrict__ pcnt, const int* __restrict__ ebase,
    unsigned* __restrict__ ebuf, const int* __restrict__ flag) {
  extern __shared__ int lds2[];
  int* base_l = lds2;       // nb
  int* cur    = lds2 + nb;  // nb
  const int t = threadIdx.x;
  for (int i = t; i < nb; i += 256) {
    base_l[i] = ebase[i] + pcnt[(size_t)i * NPB + blockIdx.x];
    cur[i] = 0;
  }
  __syncthreads();
  const int f = *flag;
  const int chunk = (e + NPB - 1) / NPB;
  const int lo = blockIdx.x * chunk;
  const int hi = min(lo + chunk, e);
  for (int i = lo + t; i < hi; i += 256) {
    int s, d;
    if (f) { s = ei[i]; d = ei[e + i]; }
    else {
      s = (int)(((const long long*)ei)[i]);
      d = (int)(((const long long*)ei)[e + i]);
    }
    s = min(max(s, 0), n - 1);
    d = min(max(d, 0), n - 1);
    int b = d >> BSHIFT;
    int slot = atomicAdd(&cur[b], 1);
    ebuf[base_l[b] + slot] = ((unsigned)(d & (BW - 1)) << 23) | (unsigned)s;
  }
}

// ---- per-bucket finalize: degree, scan, row_ptr, dinv, col scatter ---------

__global__ __launch_bounds__(256) void k_finalize(const unsigned* __restrict__ ebuf,
    const int* __restrict__ ebase, const int* __restrict__ cbase, int n, int nb,
    int* __restrict__ row_ptr, float* __restrict__ dinv, int* __restrict__ col) {
  __shared__ int ldeg[BW];
  __shared__ int lofs[BW];
  __shared__ int lcur[BW];
  __shared__ int wsum[256];
  const int b = blockIdx.x;
  const int t = threadIdx.x;
  const int lo = b * BW;
  const int nn = min(BW, n - lo);
  const int eb = ebase[b], ee = ebase[b + 1];
  const int cb = cbase[b];
  for (int k = t; k < BW; k += 256) ldeg[k] = 0;
  __syncthreads();
  for (int k = t; k < nn; k += 256) ldeg[k] = 1;  // self-loop
  __syncthreads();
  for (int j = eb + t; j < ee; j += 256) {
    int dl = (int)(ebuf[j] >> 23);
    atomicAdd(&ldeg[dl], 1);
  }
  __syncthreads();
  int p0 = ldeg[2 * t], p1 = ldeg[2 * t + 1];
  wsum[t] = p0 + p1;
  __syncthreads();
  for (int off = 1; off < 256; off <<= 1) {
    int v = (t >= off) ? wsum[t - off] : 0;
    __syncthreads();
    wsum[t] += v;
    __syncthreads();
  }
  int pb = (t == 0) ? 0 : wsum[t - 1];
  lofs[2 * t] = pb;
  lofs[2 * t + 1] = pb + p0;
  __syncthreads();
  for (int k = t; k < nn; k += 256) {
    int base = cb + lofs[k];
    row_ptr[lo + k] = base;
    dinv[lo + k] = rsqrtf((float)ldeg[k]);
    col[base] = lo + k;          // self-loop entry
    lcur[k] = lofs[k] + 1;
  }
  if (b == nb - 1 && t == 0) row_ptr[n] = cbase[nb];
  __syncthreads();
  for (int j = eb + t; j < ee; j += 256) {
    unsigned pk = ebuf[j];
    int s = (int)(pk & 0x7FFFFF);
    int dl = (int)(pk >> 23);
    int p = atomicAdd(&lcur[dl], 1);
    col[cb + p] = s;
  }
}

// ---- feature prescale: fp32 -> bf16, *dinv[row] ----------------------------

__global__ void k_scale(const float* __restrict__ x, const float* __restrict__ dinv,
                        unsigned short* __restrict__ xs, int nrows) {
  int i = blockIdx.x * blockDim.x + threadIdx.x;   // one float4 group
  int total4 = nrows * 16;                          // 16 float4 per row
  if (i >= total4) return;
  float sc = dinv[i >> 4];
  float4 v = ((const float4*)x)[i];
  ushort4 o;
  o.x = f2bf(v.x * sc); o.y = f2bf(v.y * sc);
  o.z = f2bf(v.z * sc); o.w = f2bf(v.w * sc);
  ((ushort4*)xs)[i] = o;
}

// ---- aggregation: bf16 gather, fp32 accum; 4 edges x 16 lanes --------------

template<bool BIAS>
__global__ __launch_bounds__(256) void k_agg(const unsigned short* __restrict__ feat,
    const int* __restrict__ row_ptr, const int* __restrict__ col,
    const float* __restrict__ dinv, const float* __restrict__ bias,
    float* __restrict__ out, int n) {
  const int wid = threadIdx.x >> 6;
  const int lane = threadIdx.x & 63;
  const int es = lane >> 4;      // edge sub-slot 0..3
  const int c4 = lane & 15;      // 4-channel group
  const int d = blockIdx.x * 4 + wid;
  if (d >= n) return;
  const int beg = row_ptr[d], end = row_ptr[d + 1];
  const ushort4* f4 = (const ushort4*)feat;
  float ax = 0.f, ay = 0.f, az = 0.f, aw = 0.f;
  int j = beg + es;
  if (j < end) {
    int s0 = col[j];
    ushort4 v0 = f4[(size_t)s0 * 16 + c4];
    for (j += 4; j < end; j += 4) {
      int s1 = col[j];
      ushort4 v1 = f4[(size_t)s1 * 16 + c4];   // in flight while v0 consumed
      ax += bf2f(v0.x); ay += bf2f(v0.y); az += bf2f(v0.z); aw += bf2f(v0.w);
      v0 = v1;
    }
    ax += bf2f(v0.x); ay += bf2f(v0.y); az += bf2f(v0.z); aw += bf2f(v0.w);
  }
#pragma unroll
  for (int off = 16; off <= 32; off <<= 1) {
    ax += __shfl_xor(ax, off);
    ay += __shfl_xor(ay, off);
    az += __shfl_xor(az, off);
    aw += __shfl_xor(aw, off);
  }
  if (es == 0) {
    float sc = dinv[d];
    ax *= sc; ay *= sc; az *= sc; aw *= sc;
    if (BIAS) {
      float4 bb = ((const float4*)bias)[c4];
      ax += bb.x; ay += bb.y; az += bb.z; aw += bb.w;
    }
    ((float4*)out)[(size_t)d * 16 + c4] = make_float4(ax, ay, az, aw);
  }
}

// ---- fp32 GEMM: [M,K] @ [K,N], W staged in LDS, 4ch x NT-node reg tile ----
// MODE 1: out = relu(acc + bias[c]) * dinv[row], fp32 out (a1s)
// MODE 2: out = acc, bf16 out (h2s)

template<int K, int N, int MODE>
__global__ __launch_bounds__(256) void k_gemm(const float* __restrict__ A,
    const float* __restrict__ W, const float* __restrict__ bias,
    const float* __restrict__ dinv, void* __restrict__ outv, int M) {
  constexpr int TILE_M = 32;
  constexpr int TILE_K = 64;
  constexpr int XS = TILE_K + 4;
  constexpr int CG = N / 4;
  constexpr int NG = 256 / CG;
  constexpr int NT = TILE_M / NG;
  __shared__ float sW[K * N];
  __shared__ float sX[TILE_M * XS];
  const int t = threadIdx.x;
  for (int i = t; i < K * N / 4; i += 256)
    ((float4*)sW)[i] = ((const float4*)W)[i];
  const int m0 = blockIdx.x * TILE_M;
  const int cg = t % CG, ng = t / CG;
  const int c0 = cg * 4;
  float4 acc[NT];
#pragma unroll
  for (int i = 0; i < NT; i++) acc[i] = make_float4(0.f, 0.f, 0.f, 0.f);
  for (int kt = 0; kt < K; kt += TILE_K) {
    __syncthreads();
    for (int i = t; i < TILE_M * TILE_K / 4; i += 256) {
      int r = i >> 4, q = i & 15;
      int row = m0 + r;
      row = row < M ? row : M - 1;
      *(float4*)&sX[r * XS + q * 4] = *(const float4*)&A[(size_t)row * K + kt + q * 4];
    }
    __syncthreads();
#pragma unroll 4
    for (int k = 0; k < TILE_K; k += 4) {
      float4 w0 = *(float4*)&sW[(kt + k + 0) * N + c0];
      float4 w1 = *(float4*)&sW[(kt + k + 1) * N + c0];
      float4 w2 = *(float4*)&sW[(kt + k + 2) * N + c0];
      float4 w3 = *(float4*)&sW[(kt + k + 3) * N + c0];
#pragma unroll
      for (int i = 0; i < NT; i++) {
        float4 xq = *(float4*)&sX[(ng * NT + i) * XS + k];
        acc[i].x += xq.x * w0.x + xq.y * w1.x + xq.z * w2.x + xq.w * w3.x;
        acc[i].y += xq.x * w0.y + xq.y * w1.y + xq.z * w2.y + xq.w * w3.y;
        acc[i].z += xq.x * w0.z + xq.y * w1.z + xq.z * w2.z + xq.w * w3.z;
        acc[i].w += xq.x * w0.w + xq.y * w1.w + xq.z * w2.w + xq.w * w3.w;
      }
    }
  }
#pragma unroll
  for (int i = 0; i < NT; i++) {
    int nrow = m0 + ng * NT + i;
    if (nrow >= M) continue;
    float4 r = acc[i];
    if (MODE == 1) {
      float s = dinv[nrow];
      r.x = fmaxf(r.x + bias[c0 + 0], 0.f) * s;
      r.y = fmaxf(r.y + bias[c0 + 1], 0.f) * s;
      r.z = fmaxf(r.z + bias[c0 + 2], 0.f) * s;
      r.w = fmaxf(r.w + bias[c0 + 3], 0.f) * s;
      *(float4*)&((float*)outv)[(size_t)nrow * N + c0] = r;
    } else {
      ushort4 o;
      o.x = f2bf(r.x); o.y = f2bf(r.y); o.z = f2bf(r.z); o.w = f2bf(r.w);
      *(ushort4*)&((unsigned short*)outv)[(size_t)nrow * N + c0] = o;
    }
  }
}

// ---- launch ---------------------------------------------------------------

extern "C" void kernel_launch(void* const* d_in, const int* in_sizes, int n_in,
                              void* d_out, int out_size, void* d_ws, size_t ws_size,
                              hipStream_t stream) {
  const float* x  = (const float*)d_in[0];
  const int*   ei = (const int*)d_in[1];
  const float* W1 = (const float*)d_in[2];
  const float* b1 = (const float*)d_in[3];
  const float* W2 = (const float*)d_in[4];
  const float* b2 = (const float*)d_in[5];
  float* out = (float*)d_out;

  const int n = in_sizes[0] / IN_C;   // 100000
  const int e = in_sizes[1] / 2;      // 3200000
  const int nb = (n + BW - 1) >> BSHIFT;  // 196 (must be <= 256)

  char* p = (char*)d_ws;
  auto alloc = [&](size_t bytes) {
    char* r = p;
    p += (bytes + 255) & ~(size_t)255;
    return r;
  };
  int*   flag       = (int*)alloc(4);
  int*   pcnt       = (int*)alloc((size_t)nb * NPB * 4);
  int*   btot       = (int*)alloc((size_t)nb * 4);
  int*   ebase      = (int*)alloc((size_t)(nb + 1) * 4);
  int*   cbase      = (int*)alloc((size_t)(nb + 1) * 4);
  int*   row_ptr    = (int*)alloc((size_t)(n + 1) * 4);
  float* dinv       = (float*)alloc((size_t)n * 4);
  int*   col        = (int*)alloc((size_t)(e + n) * 4);
  unsigned short* xs  = (unsigned short*)alloc((size_t)n * IN_C * 2);  // bf16
  unsigned short* h2s = (unsigned short*)alloc((size_t)n * OUT_C * 2); // bf16
  float* A1         = (float*)alloc((size_t)n * IN_C * 4);
  float* a1s        = (float*)alloc((size_t)n * HID_C * 4);
  unsigned* ebuf    = (unsigned*)a1s;     // a1s live only after k_finalize

  // CSR build (two-pass radix partition, hierarchical scan)
  k_detect_i64<<<1, 256, 0, stream>>>(ei, e, flag);
  k_part1<<<NPB, 256, nb * 4, stream>>>(ei, e, n, nb, pcnt, flag);
  k_bscan<<<nb, 256, 0, stream>>>(pcnt, btot);
  k_sscan<<<1, 256, 0, stream>>>(btot, nb, n, ebase, cbase);
  k_part2<<<NPB, 256, 2 * nb * 4, stream>>>(ei, e, n, nb, pcnt, ebase, ebuf, flag);
  k_finalize<<<nb, 256, 0, stream>>>(ebuf, ebase, cbase, n, nb, row_ptr, dinv, col);

  // Layer 1: prescale x -> bf16, aggregate (64ch), GEMM 64->128 (+b1, relu, *dinv)
  k_scale<<<(n * 16 + 255) / 256, 256, 0, stream>>>(x, dinv, xs, n);
  k_agg<false><<<(n + 3) / 4, 256, 0, stream>>>(xs, row_ptr, col, dinv, nullptr, A1, n);
  k_gemm<IN_C, HID_C, 1><<<(n + 31) / 32, 256, 0, stream>>>(A1, W1, b1, dinv, a1s, n);

  // Layer 2: GEMM 128->64 -> bf16, aggregate (64ch, *dinv[d], +b2) -> fp32 out
  k_gemm<HID_C, OUT_C, 2><<<(n + 31) / 32, 256, 0, stream>>>(a1s, W2, nullptr, dinv, h2s, n);
  k_agg<true><<<(n + 3) / 4, 256, 0, stream>>>(h2s, row_ptr, col, dinv, b2, out, n);
}

// Round 7
// 380.105 us; speedup vs baseline: 3.2516x; 1.0550x over previous
//
#include <hip/hip_runtime.h>
#include <math.h>

// GCN 2-layer: N=100K nodes, E=3.2M edges (+N self loops), 64 -> 128 -> 64.
//  - Fold norm: out[d] = dinv[d] * sum_s (dinv[s]*h[s]) + b
//  - Layer 1: aggregate x first (64ch) then GEMM; layer 2: GEMM then aggregate.
//  - R6 profile: k_agg latency-bound at 6 TB/s effective (Little's law:
//    2 loads in flight x 23 waves/CU x 600cyc). R7: 4-deep gather pipeline;
//    GEMMs moved to bf16 MFMA (16x16x32), weights pre-transposed bf16.

#define IN_C 64
#define HID_C 128
#define OUT_C 64
#define BSHIFT 9
#define BW (1 << BSHIFT)          // 512 nodes per bucket
#define NPB 1024                  // partition blocks

typedef __attribute__((ext_vector_type(8))) short bf16x8;
typedef __attribute__((ext_vector_type(4))) float f32x4;

__device__ __forceinline__ float bf2f(unsigned short u) {
  return __uint_as_float((unsigned)u << 16);
}
__device__ __forceinline__ unsigned short f2bf(float f) {
  unsigned u = __float_as_uint(f);
  return (unsigned short)((u + 0x7FFF + ((u >> 16) & 1)) >> 16);  // RNE
}

// ---- int64/int32 edge layout detection ------------------------------------

__global__ void k_detect_i64(const int* __restrict__ ei, int e, int* __restrict__ flag) {
  __shared__ int any;
  if (threadIdx.x == 0) any = 0;
  __syncthreads();
  int lim = min(e, 2048);
  int found = 0;
  for (int i = threadIdx.x; i < lim; i += 256)
    if (ei[2 * i + 1] != 0) found = 1;
  if (found) atomicOr(&any, 1);
  __syncthreads();
  if (threadIdx.x == 0) *flag = any;  // 1 => int32 layout, 0 => int64 layout
}

// ---- pass 1: per-block bucket histogram (transposed store) -----------------

__global__ __launch_bounds__(256) void k_part1(const int* __restrict__ ei, int e, int n,
    int nb, int* __restrict__ pcnt, const int* __restrict__ flag) {
  extern __shared__ int lh[];
  const int t = threadIdx.x;
  for (int i = t; i < nb; i += 256) lh[i] = 0;
  __syncthreads();
  const int f = *flag;
  const int chunk = (e + NPB - 1) / NPB;
  const int lo = blockIdx.x * chunk;
  const int hi = min(lo + chunk, e);
  for (int i = lo + t; i < hi; i += 256) {
    int d = f ? ei[e + i] : (int)(((const long long*)ei)[e + i]);
    d = min(max(d, 0), n - 1);
    atomicAdd(&lh[d >> BSHIFT], 1);
  }
  __syncthreads();
  for (int i = t; i < nb; i += 256) pcnt[(size_t)i * NPB + blockIdx.x] = lh[i];
}

// ---- per-bucket parallel scan over NPB block-counts ------------------------

__global__ __launch_bounds__(256) void k_bscan(int* __restrict__ pcnt,
    int* __restrict__ btot) {
  __shared__ int ws[256];
  const int b = blockIdx.x;
  const int t = threadIdx.x;
  int* row = pcnt + (size_t)b * NPB;
  int4 v = ((int4*)row)[t];
  int s0 = v.x;
  int s1 = s0 + v.y;
  int s2 = s1 + v.z;
  int s3 = s2 + v.w;
  ws[t] = s3;
  __syncthreads();
  for (int off = 1; off < 256; off <<= 1) {
    int u = (t >= off) ? ws[t - off] : 0;
    __syncthreads();
    ws[t] += u;
    __syncthreads();
  }
  int base = (t == 0) ? 0 : ws[t - 1];
  ((int4*)row)[t] = make_int4(base, base + s0, base + s1, base + s2);
  if (t == 255) btot[b] = ws[255];
}

// ---- top-level scan: bucket totals -> ebase/cbase --------------------------

__global__ __launch_bounds__(256) void k_sscan(const int* __restrict__ btot,
    int nb, int n, int* __restrict__ ebase, int* __restrict__ cbase) {
  __shared__ int se[256], sc[256];
  const int t = threadIdx.x;
  int total = 0, nodes = 0;
  if (t < nb) {
    total = btot[t];
    nodes = min(BW, n - t * BW);
  }
  se[t] = total; sc[t] = total + nodes;
  __syncthreads();
  for (int off = 1; off < 256; off <<= 1) {
    int ve = (t >= off) ? se[t - off] : 0;
    int vc = (t >= off) ? sc[t - off] : 0;
    __syncthreads();
    se[t] += ve; sc[t] += vc;
    __syncthreads();
  }
  if (t < nb) {
    ebase[t + 1] = se[t];
    cbase[t + 1] = sc[t];
    if (t == 0) { ebase[0] = 0; cbase[0] = 0; }
  }
}

// ---- pass 2: direct partitioned scatter, u32-packed (dl:9 | src:23) --------

__global__ __launch_bounds__(256) void k_part2(const int* __restrict__ ei, int e, int n,
    int nb, const int* __restrict__ pcnt, const int* __restrict__ ebase,
    unsigned* __restrict__ ebuf, const int* __restrict__ flag) {
  extern __shared__ int lds2[];
  int* base_l = lds2;       // nb
  int* cur    = lds2 + nb;  // nb
  const int t = threadIdx.x;
  for (int i = t; i < nb; i += 256) {
    base_l[i] = ebase[i] + pcnt[(size_t)i * NPB + blockIdx.x];
    cur[i] = 0;
  }
  __syncthreads();
  const int f = *flag;
  const int chunk = (e + NPB - 1) / NPB;
  const int lo = blockIdx.x * chunk;
  const int hi = min(lo + chunk, e);
  for (int i = lo + t; i < hi; i += 256) {
    int s, d;
    if (f) { s = ei[i]; d = ei[e + i]; }
    else {
      s = (int)(((const long long*)ei)[i]);
      d = (int)(((const long long*)ei)[e + i]);
    }
    s = min(max(s, 0), n - 1);
    d = min(max(d, 0), n - 1);
    int b = d >> BSHIFT;
    int slot = atomicAdd(&cur[b], 1);
    ebuf[base_l[b] + slot] = ((unsigned)(d & (BW - 1)) << 23) | (unsigned)s;
  }
}

// ---- per-bucket finalize: degree, scan, row_ptr, dinv, col scatter ---------

__global__ __launch_bounds__(256) void k_finalize(const unsigned* __restrict__ ebuf,
    const int* __restrict__ ebase, const int* __restrict__ cbase, int n, int nb,
    int* __restrict__ row_ptr, float* __restrict__ dinv, int* __restrict__ col) {
  __shared__ int ldeg[BW];
  __shared__ int lofs[BW];
  __shared__ int lcur[BW];
  __shared__ int wsum[256];
  const int b = blockIdx.x;
  const int t = threadIdx.x;
  const int lo = b * BW;
  const int nn = min(BW, n - lo);
  const int eb = ebase[b], ee = ebase[b + 1];
  const int cb = cbase[b];
  for (int k = t; k < BW; k += 256) ldeg[k] = 0;
  __syncthreads();
  for (int k = t; k < nn; k += 256) ldeg[k] = 1;  // self-loop
  __syncthreads();
  for (int j = eb + t; j < ee; j += 256) {
    int dl = (int)(ebuf[j] >> 23);
    atomicAdd(&ldeg[dl], 1);
  }
  __syncthreads();
  int p0 = ldeg[2 * t], p1 = ldeg[2 * t + 1];
  wsum[t] = p0 + p1;
  __syncthreads();
  for (int off = 1; off < 256; off <<= 1) {
    int v = (t >= off) ? wsum[t - off] : 0;
    __syncthreads();
    wsum[t] += v;
    __syncthreads();
  }
  int pb = (t == 0) ? 0 : wsum[t - 1];
  lofs[2 * t] = pb;
  lofs[2 * t + 1] = pb + p0;
  __syncthreads();
  for (int k = t; k < nn; k += 256) {
    int base = cb + lofs[k];
    row_ptr[lo + k] = base;
    dinv[lo + k] = rsqrtf((float)ldeg[k]);
    col[base] = lo + k;          // self-loop entry
    lcur[k] = lofs[k] + 1;
  }
  if (b == nb - 1 && t == 0) row_ptr[n] = cbase[nb];
  __syncthreads();
  for (int j = eb + t; j < ee; j += 256) {
    unsigned pk = ebuf[j];
    int s = (int)(pk & 0x7FFFFF);
    int dl = (int)(pk >> 23);
    int p = atomicAdd(&lcur[dl], 1);
    col[cb + p] = s;
  }
}

// ---- feature prescale: fp32 -> bf16, *dinv[row] ----------------------------

__global__ void k_scale(const float* __restrict__ x, const float* __restrict__ dinv,
                        unsigned short* __restrict__ xs, int nrows) {
  int i = blockIdx.x * blockDim.x + threadIdx.x;   // one float4 group
  int total4 = nrows * 16;                          // 16 float4 per row
  if (i >= total4) return;
  float sc = dinv[i >> 4];
  float4 v = ((const float4*)x)[i];
  ushort4 o;
  o.x = f2bf(v.x * sc); o.y = f2bf(v.y * sc);
  o.z = f2bf(v.z * sc); o.w = f2bf(v.w * sc);
  ((ushort4*)xs)[i] = o;
}

// ---- weight convert+transpose: W[K x N] fp32 -> Wt[N x K] bf16 -------------

__global__ void k_wconv(const float* __restrict__ W1, const float* __restrict__ W2,
                        unsigned short* __restrict__ Wt1, unsigned short* __restrict__ Wt2) {
  int i = blockIdx.x * 256 + threadIdx.x;
  if (i < IN_C * HID_C) {
    int k = i >> 7, c = i & (HID_C - 1);           // W1[k][c]
    Wt1[c * IN_C + k] = f2bf(W1[i]);
  }
  if (i < HID_C * OUT_C) {
    int k = i >> 6, c = i & (OUT_C - 1);           // W2[k][c]
    Wt2[c * HID_C + k] = f2bf(W2[i]);
  }
}

// ---- aggregation: bf16 gather, fp32 accum; 4 edges x 16 lanes, 4-deep ------

template<bool BIAS, bool OUT_BF16>
__global__ __launch_bounds__(256) void k_agg(const unsigned short* __restrict__ feat,
    const int* __restrict__ row_ptr, const int* __restrict__ col,
    const float* __restrict__ dinv, const float* __restrict__ bias,
    void* __restrict__ outv, int n) {
  const int wid = threadIdx.x >> 6;
  const int lane = threadIdx.x & 63;
  const int es = lane >> 4;      // edge sub-slot 0..3
  const int c4 = lane & 15;      // 4-channel group
  const int d = blockIdx.x * 4 + wid;
  if (d >= n) return;
  const int beg = row_ptr[d], end = row_ptr[d + 1];
  const ushort4* f4 = (const ushort4*)feat;
  float ax = 0.f, ay = 0.f, az = 0.f, aw = 0.f;
  int j = beg + es;
  // 4-deep pipelined main loop: 4 independent gathers in flight per slot
  for (; j + 12 < end; j += 16) {
    int s0 = col[j], s1 = col[j + 4], s2 = col[j + 8], s3 = col[j + 12];
    ushort4 v0 = f4[(size_t)s0 * 16 + c4];
    ushort4 v1 = f4[(size_t)s1 * 16 + c4];
    ushort4 v2 = f4[(size_t)s2 * 16 + c4];
    ushort4 v3 = f4[(size_t)s3 * 16 + c4];
    ax += bf2f(v0.x) + bf2f(v1.x) + bf2f(v2.x) + bf2f(v3.x);
    ay += bf2f(v0.y) + bf2f(v1.y) + bf2f(v2.y) + bf2f(v3.y);
    az += bf2f(v0.z) + bf2f(v1.z) + bf2f(v2.z) + bf2f(v3.z);
    aw += bf2f(v0.w) + bf2f(v1.w) + bf2f(v2.w) + bf2f(v3.w);
  }
  for (; j < end; j += 4) {
    int s = col[j];
    ushort4 v = f4[(size_t)s * 16 + c4];
    ax += bf2f(v.x); ay += bf2f(v.y); az += bf2f(v.z); aw += bf2f(v.w);
  }
#pragma unroll
  for (int off = 16; off <= 32; off <<= 1) {
    ax += __shfl_xor(ax, off);
    ay += __shfl_xor(ay, off);
    az += __shfl_xor(az, off);
    aw += __shfl_xor(aw, off);
  }
  if (es == 0) {
    float sc = dinv[d];
    ax *= sc; ay *= sc; az *= sc; aw *= sc;
    if (BIAS) {
      float4 bb = ((const float4*)bias)[c4];
      ax += bb.x; ay += bb.y; az += bb.z; aw += bb.w;
    }
    if (OUT_BF16) {
      ushort4 o;
      o.x = f2bf(ax); o.y = f2bf(ay); o.z = f2bf(az); o.w = f2bf(aw);
      ((ushort4*)outv)[(size_t)d * 16 + c4] = o;
    } else {
      ((float4*)outv)[(size_t)d * 16 + c4] = make_float4(ax, ay, az, aw);
    }
  }
}

// ---- MFMA bf16 GEMM: out[M x N] = A[M x K] @ Wt[N x K]^T -------------------
// block = 4 waves, 16 rows; wave w covers col-tiles {w, w+4, ...}
// MODE 1: out = bf16(relu(acc + bias[c]) * dinv[row]); MODE 2: out = bf16(acc)

template<int K, int N, int MODE>
__global__ __launch_bounds__(256) void k_mgemm(const unsigned short* __restrict__ A,
    const unsigned short* __restrict__ Wt, const float* __restrict__ bias,
    const float* __restrict__ dinv, unsigned short* __restrict__ out, int M) {
  constexpr int CT = (N / 16) / 4;       // col-tiles per wave (>=1)
  const int wv = threadIdx.x >> 6;
  const int lane = threadIdx.x & 63;
  const int m = lane & 15;               // A-row / C-col within tile
  const int q = lane >> 4;               // quad: k-group / C-row group
  const int r0 = blockIdx.x * 16;
  const int ra = min(r0 + m, M - 1);     // clamped A row
  f32x4 acc[CT];
#pragma unroll
  for (int i = 0; i < CT; i++) acc[i] = (f32x4){0.f, 0.f, 0.f, 0.f};
#pragma unroll
  for (int kt = 0; kt < K; kt += 32) {
    bf16x8 a = *(const bf16x8*)&A[(size_t)ra * K + kt + q * 8];
#pragma unroll
    for (int ct = 0; ct < CT; ct++) {
      int c0 = (wv + ct * 4) * 16;
      bf16x8 b = *(const bf16x8*)&Wt[(size_t)(c0 + m) * K + kt + q * 8];
      acc[ct] = __builtin_amdgcn_mfma_f32_16x16x32_bf16(a, b, acc[ct], 0, 0, 0);
    }
  }
#pragma unroll
  for (int ct = 0; ct < CT; ct++) {
    int c = (wv + ct * 4) * 16 + m;      // C col = lane&15
    float bv = (MODE == 1) ? bias[c] : 0.f;
#pragma unroll
    for (int i = 0; i < 4; i++) {
      int row = r0 + q * 4 + i;          // C row = quad*4 + reg
      if (row >= M) continue;
      float v = acc[ct][i];
      if (MODE == 1) v = fmaxf(v + bv, 0.f) * dinv[row];
      out[(size_t)row * N + c] = f2bf(v);
    }
  }
}

// ---- launch ---------------------------------------------------------------

extern "C" void kernel_launch(void* const* d_in, const int* in_sizes, int n_in,
                              void* d_out, int out_size, void* d_ws, size_t ws_size,
                              hipStream_t stream) {
  const float* x  = (const float*)d_in[0];
  const int*   ei = (const int*)d_in[1];
  const float* W1 = (const float*)d_in[2];
  const float* b1 = (const float*)d_in[3];
  const float* W2 = (const float*)d_in[4];
  const float* b2 = (const float*)d_in[5];
  float* out = (float*)d_out;

  const int n = in_sizes[0] / IN_C;   // 100000
  const int e = in_sizes[1] / 2;      // 3200000
  const int nb = (n + BW - 1) >> BSHIFT;  // 196 (must be <= 256)

  char* p = (char*)d_ws;
  auto alloc = [&](size_t bytes) {
    char* r = p;
    p += (bytes + 255) & ~(size_t)255;
    return r;
  };
  int*   flag       = (int*)alloc(4);
  int*   pcnt       = (int*)alloc((size_t)nb * NPB * 4);
  int*   btot       = (int*)alloc((size_t)nb * 4);
  int*   ebase      = (int*)alloc((size_t)(nb + 1) * 4);
  int*   cbase      = (int*)alloc((size_t)(nb + 1) * 4);
  int*   row_ptr    = (int*)alloc((size_t)(n + 1) * 4);
  float* dinv       = (float*)alloc((size_t)n * 4);
  int*   col        = (int*)alloc((size_t)(e + n) * 4);
  unsigned* ebuf    = (unsigned*)alloc((size_t)e * 4);
  unsigned short* xs  = (unsigned short*)alloc((size_t)n * IN_C * 2);   // bf16
  unsigned short* A1  = (unsigned short*)alloc((size_t)n * IN_C * 2);   // bf16
  unsigned short* a1s = (unsigned short*)alloc((size_t)n * HID_C * 2);  // bf16
  unsigned short* h2s = (unsigned short*)alloc((size_t)n * OUT_C * 2);  // bf16
  unsigned short* Wt1 = (unsigned short*)alloc((size_t)IN_C * HID_C * 2);
  unsigned short* Wt2 = (unsigned short*)alloc((size_t)HID_C * OUT_C * 2);

  // CSR build (two-pass radix partition, hierarchical scan)
  k_detect_i64<<<1, 256, 0, stream>>>(ei, e, flag);
  k_part1<<<NPB, 256, nb * 4, stream>>>(ei, e, n, nb, pcnt, flag);
  k_bscan<<<nb, 256, 0, stream>>>(pcnt, btot);
  k_sscan<<<1, 256, 0, stream>>>(btot, nb, n, ebase, cbase);
  k_part2<<<NPB, 256, 2 * nb * 4, stream>>>(ei, e, n, nb, pcnt, ebase, ebuf, flag);
  k_finalize<<<nb, 256, 0, stream>>>(ebuf, ebase, cbase, n, nb, row_ptr, dinv, col);

  // weights -> bf16 transposed
  k_wconv<<<(HID_C * IN_C + 255) / 256, 256, 0, stream>>>(W1, W2, Wt1, Wt2);

  // Layer 1: prescale x -> bf16, aggregate -> bf16 A1, MFMA GEMM 64->128
  k_scale<<<(n * 16 + 255) / 256, 256, 0, stream>>>(x, dinv, xs, n);
  k_agg<false, true><<<(n + 3) / 4, 256, 0, stream>>>(xs, row_ptr, col, dinv, nullptr, A1, n);
  k_mgemm<IN_C, HID_C, 1><<<(n + 15) / 16, 256, 0, stream>>>(A1, Wt1, b1, dinv, a1s, n);

  // Layer 2: MFMA GEMM 128->64 -> bf16 h2s, aggregate (+b2) -> fp32 out
  k_mgemm<HID_C, OUT_C, 2><<<(n + 15) / 16, 256, 0, stream>>>(a1s, Wt2, nullptr, nullptr, h2s, n);
  k_agg<true, false><<<(n + 3) / 4, 256, 0, stream>>>(h2s, row_ptr, col, dinv, b2, out, n);
}

// Round 8
// 365.959 us; speedup vs baseline: 3.3773x; 1.0387x over previous
//
#include <hip/hip_runtime.h>
#include <math.h>

// GCN 2-layer: N=100K nodes, E=3.2M edges (+N self loops), 64 -> 128 -> 64.
//  - Fold norm: out[d] = dinv[d] * sum_s (dinv[s]*h[s]) + b
//  - Layer 1: aggregate x first (64ch) then GEMM; layer 2: GEMM then aggregate.
//  - R7 profile: 4-deep agg pipeline only fired once per slot (deg~33 -> 8
//    edges/slot, remainder loop 1-deep). R8: masked 4-deep pipeline over ALL
//    edges via zero-row-at-n trick; k_sscan folded into part2/finalize;
//    detect+wconv merged; nontemporal ei streams.

#define IN_C 64
#define HID_C 128
#define OUT_C 64
#define BSHIFT 9
#define BW (1 << BSHIFT)          // 512 nodes per bucket
#define NPB 1024                  // partition blocks

typedef __attribute__((ext_vector_type(8))) short bf16x8;
typedef __attribute__((ext_vector_type(4))) float f32x4;

__device__ __forceinline__ float bf2f(unsigned short u) {
  return __uint_as_float((unsigned)u << 16);
}
__device__ __forceinline__ unsigned short f2bf(float f) {
  unsigned u = __float_as_uint(f);
  return (unsigned short)((u + 0x7FFF + ((u >> 16) & 1)) >> 16);  // RNE
}

// ---- prep: int64 detect (block 0) + h2s zero row + weight convert ----------

__global__ void k_prep(const int* __restrict__ ei, int e, int* __restrict__ flag,
                       const float* __restrict__ W1, const float* __restrict__ W2,
                       unsigned short* __restrict__ Wt1, unsigned short* __restrict__ Wt2,
                       unsigned short* __restrict__ h2s_zero_row) {
  if (blockIdx.x == 0) {
    __shared__ int any;
    if (threadIdx.x == 0) any = 0;
    __syncthreads();
    int lim = min(e, 2048);
    int found = 0;
    for (int i = threadIdx.x; i < lim; i += 256)
      if (ei[2 * i + 1] != 0) found = 1;
    if (found) atomicOr(&any, 1);
    __syncthreads();
    if (threadIdx.x == 0) *flag = any;  // 1 => int32 layout, 0 => int64 layout
    if (threadIdx.x < OUT_C) h2s_zero_row[threadIdx.x] = 0;
    return;
  }
  int i = (blockIdx.x - 1) * 256 + threadIdx.x;
  if (i < IN_C * HID_C) {
    int k = i >> 7, c = i & (HID_C - 1);           // W1[k][c]
    Wt1[c * IN_C + k] = f2bf(W1[i]);
  }
  if (i < HID_C * OUT_C) {
    int k = i >> 6, c = i & (OUT_C - 1);           // W2[k][c]
    Wt2[c * HID_C + k] = f2bf(W2[i]);
  }
}

// ---- pass 1: per-block bucket histogram (transposed store) -----------------

__global__ __launch_bounds__(256) void k_part1(const int* __restrict__ ei, int e, int n,
    int nb, int* __restrict__ pcnt, const int* __restrict__ flag) {
  extern __shared__ int lh[];
  const int t = threadIdx.x;
  for (int i = t; i < nb; i += 256) lh[i] = 0;
  __syncthreads();
  const int f = *flag;
  const int chunk = (e + NPB - 1) / NPB;
  const int lo = blockIdx.x * chunk;
  const int hi = min(lo + chunk, e);
  for (int i = lo + t; i < hi; i += 256) {
    int d;
    if (f) d = __builtin_nontemporal_load(&ei[e + i]);
    else   d = (int)__builtin_nontemporal_load(&((const long long*)ei)[e + i]);
    d = min(max(d, 0), n - 1);
    atomicAdd(&lh[d >> BSHIFT], 1);
  }
  __syncthreads();
  for (int i = t; i < nb; i += 256) pcnt[(size_t)i * NPB + blockIdx.x] = lh[i];
}

// ---- per-bucket parallel scan over NPB block-counts ------------------------

__global__ __launch_bounds__(256) void k_bscan(int* __restrict__ pcnt,
    int* __restrict__ btot) {
  __shared__ int ws[256];
  const int b = blockIdx.x;
  const int t = threadIdx.x;
  int* row = pcnt + (size_t)b * NPB;
  int4 v = ((int4*)row)[t];
  int s0 = v.x;
  int s1 = s0 + v.y;
  int s2 = s1 + v.z;
  int s3 = s2 + v.w;
  ws[t] = s3;
  __syncthreads();
  for (int off = 1; off < 256; off <<= 1) {
    int u = (t >= off) ? ws[t - off] : 0;
    __syncthreads();
    ws[t] += u;
    __syncthreads();
  }
  int base = (t == 0) ? 0 : ws[t - 1];
  ((int4*)row)[t] = make_int4(base, base + s0, base + s1, base + s2);
  if (t == 255) btot[b] = ws[255];
}

// ---- pass 2: direct partitioned scatter, u32-packed (dl:9 | src:23) --------
// ebase recomputed in-block from btot (196-elem scan, ~free)

__global__ __launch_bounds__(256) void k_part2(const int* __restrict__ ei, int e, int n,
    int nb, const int* __restrict__ pcnt, const int* __restrict__ btot,
    unsigned* __restrict__ ebuf, const int* __restrict__ flag) {
  __shared__ int se[256];
  __shared__ int base_l[256];
  __shared__ int cur[256];
  const int t = threadIdx.x;
  se[t] = (t < nb) ? btot[t] : 0;
  __syncthreads();
  for (int off = 1; off < 256; off <<= 1) {
    int u = (t >= off) ? se[t - off] : 0;
    __syncthreads();
    se[t] += u;
    __syncthreads();
  }
  if (t < nb) {
    int eb = (t == 0) ? 0 : se[t - 1];
    base_l[t] = eb + pcnt[(size_t)t * NPB + blockIdx.x];
    cur[t] = 0;
  }
  __syncthreads();
  const int f = *flag;
  const int chunk = (e + NPB - 1) / NPB;
  const int lo = blockIdx.x * chunk;
  const int hi = min(lo + chunk, e);
  for (int i = lo + t; i < hi; i += 256) {
    int s, d;
    if (f) {
      s = __builtin_nontemporal_load(&ei[i]);
      d = __builtin_nontemporal_load(&ei[e + i]);
    } else {
      s = (int)__builtin_nontemporal_load(&((const long long*)ei)[i]);
      d = (int)__builtin_nontemporal_load(&((const long long*)ei)[e + i]);
    }
    s = min(max(s, 0), n - 1);
    d = min(max(d, 0), n - 1);
    int b = d >> BSHIFT;
    int slot = atomicAdd(&cur[b], 1);
    ebuf[base_l[b] + slot] = ((unsigned)(d & (BW - 1)) << 23) | (unsigned)s;
  }
}

// ---- per-bucket finalize: degree, scan, row_ptr, dinv, col scatter ---------
// ebase/cbase recomputed in-block from btot

__global__ __launch_bounds__(256) void k_finalize(const unsigned* __restrict__ ebuf,
    const int* __restrict__ btot, int n, int nb,
    int* __restrict__ row_ptr, float* __restrict__ dinv, int* __restrict__ col) {
  __shared__ int se[256], sc[256];
  __shared__ int ldeg[BW];
  __shared__ int lofs[BW];
  __shared__ int lcur[BW];
  __shared__ int wsum[256];
  const int b = blockIdx.x;
  const int t = threadIdx.x;
  // dual scan of bucket totals -> ebase/cbase
  int bc = 0, nodes = 0;
  if (t < nb) {
    bc = btot[t];
    nodes = min(BW, n - t * BW);
  }
  se[t] = bc; sc[t] = bc + nodes;
  __syncthreads();
  for (int off = 1; off < 256; off <<= 1) {
    int ve = (t >= off) ? se[t - off] : 0;
    int vc = (t >= off) ? sc[t - off] : 0;
    __syncthreads();
    se[t] += ve; sc[t] += vc;
    __syncthreads();
  }
  const int eb = (b == 0) ? 0 : se[b - 1];
  const int ee = se[b];
  const int cb = (b == 0) ? 0 : sc[b - 1];
  const int lo = b * BW;
  const int nn = min(BW, n - lo);
  for (int k = t; k < BW; k += 256) ldeg[k] = 0;
  __syncthreads();
  for (int k = t; k < nn; k += 256) ldeg[k] = 1;  // self-loop
  __syncthreads();
  for (int j = eb + t; j < ee; j += 256) {
    int dl = (int)(ebuf[j] >> 23);
    atomicAdd(&ldeg[dl], 1);
  }
  __syncthreads();
  int p0 = ldeg[2 * t], p1 = ldeg[2 * t + 1];
  wsum[t] = p0 + p1;
  __syncthreads();
  for (int off = 1; off < 256; off <<= 1) {
    int v = (t >= off) ? wsum[t - off] : 0;
    __syncthreads();
    wsum[t] += v;
    __syncthreads();
  }
  int pb = (t == 0) ? 0 : wsum[t - 1];
  lofs[2 * t] = pb;
  lofs[2 * t + 1] = pb + p0;
  __syncthreads();
  for (int k = t; k < nn; k += 256) {
    int base = cb + lofs[k];
    row_ptr[lo + k] = base;
    dinv[lo + k] = rsqrtf((float)ldeg[k]);
    col[base] = lo + k;          // self-loop entry
    lcur[k] = lofs[k] + 1;
  }
  if (b == nb - 1 && t == 0) row_ptr[n] = sc[nb - 1];
  __syncthreads();
  for (int j = eb + t; j < ee; j += 256) {
    unsigned pk = ebuf[j];
    int s = (int)(pk & 0x7FFFFF);
    int dl = (int)(pk >> 23);
    int p = atomicAdd(&lcur[dl], 1);
    col[cb + p] = s;
  }
}

// ---- feature prescale: fp32 -> bf16, *dinv[row]; zero row at n -------------

__global__ void k_scale(const float* __restrict__ x, const float* __restrict__ dinv,
                        unsigned short* __restrict__ xs, int nrows) {
  int i = blockIdx.x * blockDim.x + threadIdx.x;   // one float4 group
  int total4 = (nrows + 1) * 16;                   // incl. zero row
  if (i >= total4) return;
  int row = i >> 4;
  ushort4 o;
  if (row >= nrows) {
    o.x = o.y = o.z = o.w = 0;
  } else {
    float sc = dinv[row];
    float4 v = ((const float4*)x)[i];
    o.x = f2bf(v.x * sc); o.y = f2bf(v.y * sc);
    o.z = f2bf(v.z * sc); o.w = f2bf(v.w * sc);
  }
  ((ushort4*)xs)[i] = o;
}

// ---- aggregation: bf16 gather, fp32 accum; masked 4-deep pipeline ----------
// feat must have a zero row at index n.

template<bool BIAS, bool OUT_BF16>
__global__ __launch_bounds__(256) void k_agg(const unsigned short* __restrict__ feat,
    const int* __restrict__ row_ptr, const int* __restrict__ col,
    const float* __restrict__ dinv, const float* __restrict__ bias,
    void* __restrict__ outv, int n) {
  const int wid = threadIdx.x >> 6;
  const int lane = threadIdx.x & 63;
  const int es = lane >> 4;      // edge sub-slot 0..3
  const int c4 = lane & 15;      // 4-channel group
  const int d = blockIdx.x * 4 + wid;
  if (d >= n) return;
  const int beg = row_ptr[d], end = row_ptr[d + 1];
  const ushort4* f4 = (const ushort4*)feat;
  float ax = 0.f, ay = 0.f, az = 0.f, aw = 0.f;
  // slot-local count: edges at beg+es, beg+es+4, ...
  const int rem = end - beg - es;
  const int c = (rem > 0) ? ((rem + 3) >> 2) : 0;
  for (int t = 0; t < c; t += 4) {
    int j0 = beg + es + 4 * t;
    // unconditional clamped col loads; invalid -> zero row n
    int s0 = col[j0];
    int s1 = col[min(j0 + 4, end - 1)];
    int s2 = col[min(j0 + 8, end - 1)];
    int s3 = col[min(j0 + 12, end - 1)];
    if (t + 1 >= c) s1 = n;
    if (t + 2 >= c) s2 = n;
    if (t + 3 >= c) s3 = n;
    ushort4 v0 = f4[(size_t)s0 * 16 + c4];
    ushort4 v1 = f4[(size_t)s1 * 16 + c4];
    ushort4 v2 = f4[(size_t)s2 * 16 + c4];
    ushort4 v3 = f4[(size_t)s3 * 16 + c4];
    ax += bf2f(v0.x) + bf2f(v1.x) + bf2f(v2.x) + bf2f(v3.x);
    ay += bf2f(v0.y) + bf2f(v1.y) + bf2f(v2.y) + bf2f(v3.y);
    az += bf2f(v0.z) + bf2f(v1.z) + bf2f(v2.z) + bf2f(v3.z);
    aw += bf2f(v0.w) + bf2f(v1.w) + bf2f(v2.w) + bf2f(v3.w);
  }
#pragma unroll
  for (int off = 16; off <= 32; off <<= 1) {
    ax += __shfl_xor(ax, off);
    ay += __shfl_xor(ay, off);
    az += __shfl_xor(az, off);
    aw += __shfl_xor(aw, off);
  }
  if (es == 0) {
    float sc = dinv[d];
    ax *= sc; ay *= sc; az *= sc; aw *= sc;
    if (BIAS) {
      float4 bb = ((const float4*)bias)[c4];
      ax += bb.x; ay += bb.y; az += bb.z; aw += bb.w;
    }
    if (OUT_BF16) {
      ushort4 o;
      o.x = f2bf(ax); o.y = f2bf(ay); o.z = f2bf(az); o.w = f2bf(aw);
      ((ushort4*)outv)[(size_t)d * 16 + c4] = o;
    } else {
      ((float4*)outv)[(size_t)d * 16 + c4] = make_float4(ax, ay, az, aw);
    }
  }
}

// ---- MFMA bf16 GEMM: out[M x N] = A[M x K] @ Wt[N x K]^T -------------------
// block = 4 waves, 16 rows; wave w covers col-tiles {w, w+4, ...}
// MODE 1: out = bf16(relu(acc + bias[c]) * dinv[row]); MODE 2: out = bf16(acc)

template<int K, int N, int MODE>
__global__ __launch_bounds__(256) void k_mgemm(const unsigned short* __restrict__ A,
    const unsigned short* __restrict__ Wt, const float* __restrict__ bias,
    const float* __restrict__ dinv, unsigned short* __restrict__ out, int M) {
  constexpr int CT = (N / 16) / 4;       // col-tiles per wave (>=1)
  const int wv = threadIdx.x >> 6;
  const int lane = threadIdx.x & 63;
  const int m = lane & 15;               // A-row / C-col within tile
  const int q = lane >> 4;               // quad: k-group / C-row group
  const int r0 = blockIdx.x * 16;
  const int ra = min(r0 + m, M - 1);     // clamped A row
  f32x4 acc[CT];
#pragma unroll
  for (int i = 0; i < CT; i++) acc[i] = (f32x4){0.f, 0.f, 0.f, 0.f};
#pragma unroll
  for (int kt = 0; kt < K; kt += 32) {
    bf16x8 a = *(const bf16x8*)&A[(size_t)ra * K + kt + q * 8];
#pragma unroll
    for (int ct = 0; ct < CT; ct++) {
      int c0 = (wv + ct * 4) * 16;
      bf16x8 b = *(const bf16x8*)&Wt[(size_t)(c0 + m) * K + kt + q * 8];
      acc[ct] = __builtin_amdgcn_mfma_f32_16x16x32_bf16(a, b, acc[ct], 0, 0, 0);
    }
  }
#pragma unroll
  for (int ct = 0; ct < CT; ct++) {
    int c = (wv + ct * 4) * 16 + m;      // C col = lane&15
    float bv = (MODE == 1) ? bias[c] : 0.f;
#pragma unroll
    for (int i = 0; i < 4; i++) {
      int row = r0 + q * 4 + i;          // C row = quad*4 + reg
      if (row >= M) continue;
      float v = acc[ct][i];
      if (MODE == 1) v = fmaxf(v + bv, 0.f) * dinv[row];
      out[(size_t)row * N + c] = f2bf(v);
    }
  }
}

// ---- launch ---------------------------------------------------------------

extern "C" void kernel_launch(void* const* d_in, const int* in_sizes, int n_in,
                              void* d_out, int out_size, void* d_ws, size_t ws_size,
                              hipStream_t stream) {
  const float* x  = (const float*)d_in[0];
  const int*   ei = (const int*)d_in[1];
  const float* W1 = (const float*)d_in[2];
  const float* b1 = (const float*)d_in[3];
  const float* W2 = (const float*)d_in[4];
  const float* b2 = (const float*)d_in[5];
  float* out = (float*)d_out;

  const int n = in_sizes[0] / IN_C;   // 100000
  const int e = in_sizes[1] / 2;      // 3200000
  const int nb = (n + BW - 1) >> BSHIFT;  // 196 (must be <= 256)

  char* p = (char*)d_ws;
  auto alloc = [&](size_t bytes) {
    char* r = p;
    p += (bytes + 255) & ~(size_t)255;
    return r;
  };
  int*   flag       = (int*)alloc(4);
  int*   pcnt       = (int*)alloc((size_t)nb * NPB * 4);
  int*   btot       = (int*)alloc((size_t)nb * 4);
  int*   row_ptr    = (int*)alloc((size_t)(n + 1) * 4);
  float* dinv       = (float*)alloc((size_t)n * 4);
  int*   col        = (int*)alloc((size_t)(e + n) * 4);
  unsigned* ebuf    = (unsigned*)alloc((size_t)e * 4);
  unsigned short* xs  = (unsigned short*)alloc((size_t)(n + 1) * IN_C * 2);   // bf16 + zero row
  unsigned short* A1  = (unsigned short*)alloc((size_t)n * IN_C * 2);         // bf16
  unsigned short* a1s = (unsigned short*)alloc((size_t)n * HID_C * 2);        // bf16
  unsigned short* h2s = (unsigned short*)alloc((size_t)(n + 1) * OUT_C * 2);  // bf16 + zero row
  unsigned short* Wt1 = (unsigned short*)alloc((size_t)IN_C * HID_C * 2);
  unsigned short* Wt2 = (unsigned short*)alloc((size_t)HID_C * OUT_C * 2);

  // prep (detect + wconv + h2s zero row)
  k_prep<<<1 + (IN_C * HID_C + 255) / 256, 256, 0, stream>>>(
      ei, e, flag, W1, W2, Wt1, Wt2, h2s + (size_t)n * OUT_C);

  // CSR build (two-pass radix partition, hierarchical scan)
  k_part1<<<NPB, 256, nb * 4, stream>>>(ei, e, n, nb, pcnt, flag);
  k_bscan<<<nb, 256, 0, stream>>>(pcnt, btot);
  k_part2<<<NPB, 256, 0, stream>>>(ei, e, n, nb, pcnt, btot, ebuf, flag);
  k_finalize<<<nb, 256, 0, stream>>>(ebuf, btot, n, nb, row_ptr, dinv, col);

  // Layer 1: prescale x -> bf16 (+zero row), aggregate -> bf16 A1, MFMA GEMM
  k_scale<<<((n + 1) * 16 + 255) / 256, 256, 0, stream>>>(x, dinv, xs, n);
  k_agg<false, true><<<(n + 3) / 4, 256, 0, stream>>>(xs, row_ptr, col, dinv, nullptr, A1, n);
  k_mgemm<IN_C, HID_C, 1><<<(n + 15) / 16, 256, 0, stream>>>(A1, Wt1, b1, dinv, a1s, n);

  // Layer 2: MFMA GEMM 128->64 -> bf16 h2s, aggregate (+b2) -> fp32 out
  k_mgemm<HID_C, OUT_C, 2><<<(n + 15) / 16, 256, 0, stream>>>(a1s, Wt2, nullptr, nullptr, h2s, n);
  k_agg<true, false><<<(n + 3) / 4, 256, 0, stream>>>(h2s, row_ptr, col, dinv, b2, out, n);
}

// Round 10
// 333.758 us; speedup vs baseline: 3.7032x; 1.0965x over previous
//
#include <hip/hip_runtime.h>
#include <math.h>

// GCN 2-layer: N=100K nodes, E=3.2M edges (+N self loops), 64 -> 128 -> 64.
//  - Fold norm: out[d] = dinv[d] * sum_s (dinv[s]*h[s]) + b
//  - R8 profile: agg half-VALU-bound (52% busy) on address/clamp ALU; ~150us
//    hidden in small kernels + 9 launch gaps. R9: agg = 8 lanes/edge x 16B
//    loads + pk_add bf16 converts; prep/scale fused away; gemm1+gemm2 fused
//    via LDS tile; NPB 1024->512 for ebuf write residency. 7 kernels total.
//    (R9 resubmit: previous round hit GPUAcquisitionTimeout, never ran.)

#define IN_C 64
#define HID_C 128
#define OUT_C 64
#define BSHIFT 9
#define BW (1 << BSHIFT)          // 512 nodes per bucket
#define NPB 512                   // partition blocks

typedef __attribute__((ext_vector_type(8))) short bf16x8;
typedef __attribute__((ext_vector_type(4))) float f32x4;
typedef __attribute__((ext_vector_type(2))) float v2f;

__device__ __forceinline__ unsigned short f2bf(float f) {
  unsigned u = __float_as_uint(f);
  return (unsigned short)((u + 0x7FFF + ((u >> 16) & 1)) >> 16);  // RNE
}
__device__ __forceinline__ v2f cvt2(unsigned u) {
  v2f r;
  r.x = __uint_as_float(u << 16);          // low bf16 -> f32
  r.y = __uint_as_float(u & 0xFFFF0000u);  // high bf16 -> f32
  return r;
}
__device__ __forceinline__ unsigned pack2(v2f v) {
  return ((unsigned)f2bf(v.y) << 16) | f2bf(v.x);
}

// ---- pass 1: detect + per-block bucket histogram + (extras: wconv, zero rows)

__global__ __launch_bounds__(256) void k_part1(const int* __restrict__ ei, int e, int n,
    int nb, int* __restrict__ pcnt,
    const float* __restrict__ W1, const float* __restrict__ W2,
    unsigned short* __restrict__ Wt1, unsigned short* __restrict__ Wt2,
    unsigned short* __restrict__ xs_zero, unsigned short* __restrict__ h2s_zero) {
  extern __shared__ int lh[];
  const int t = threadIdx.x;
  if (blockIdx.x >= NPB) {                 // extra blocks: weights + zero rows
    int bb = blockIdx.x - NPB;
    if (bb == 32) {
      if (t < 64) { xs_zero[t] = 0; h2s_zero[t] = 0; }
      return;
    }
    int i = bb * 256 + t;
    if (i < IN_C * HID_C) {
      int k = i >> 7, c = i & (HID_C - 1);
      Wt1[c * IN_C + k] = f2bf(W1[i]);
    }
    if (i < HID_C * OUT_C) {
      int k = i >> 6, c = i & (OUT_C - 1);
      Wt2[c * HID_C + k] = f2bf(W2[i]);
    }
    return;
  }
  __shared__ int sflag;
  if (t == 0) sflag = 0;
  for (int i = t; i < nb; i += 256) lh[i] = 0;
  __syncthreads();
  const int chunk = (e + NPB - 1) / NPB;
  const int lo = blockIdx.x * chunk;
  const int hi = min(lo + chunk, e);
  {  // per-chunk int32/int64 detect: odd words of int64 values (<2^31) are 0
    int lim = min(hi, lo + 512);
    int f = 0;
    for (int i = lo + t; i < lim; i += 256)
      if (ei[2 * i + 1] != 0) f = 1;
    if (f) sflag = 1;
  }
  __syncthreads();
  const int f = sflag;                     // 1 => int32 layout
  for (int i = lo + t; i < hi; i += 256) {
    int d;
    if (f) d = __builtin_nontemporal_load(&ei[e + i]);
    else   d = (int)__builtin_nontemporal_load(&((const long long*)ei)[e + i]);
    d = min(max(d, 0), n - 1);
    atomicAdd(&lh[d >> BSHIFT], 1);
  }
  __syncthreads();
  for (int i = t; i < nb; i += 256) pcnt[(size_t)i * NPB + blockIdx.x] = lh[i];
}

// ---- per-bucket parallel scan over NPB block-counts ------------------------

__global__ __launch_bounds__(256) void k_bscan(int* __restrict__ pcnt,
    int* __restrict__ btot) {
  __shared__ int ws[256];
  const int b = blockIdx.x;
  const int t = threadIdx.x;
  int* row = pcnt + (size_t)b * NPB;
  int2 v = ((int2*)row)[t];                // NPB = 512 = 256 x 2
  int s0 = v.x;
  int s1 = s0 + v.y;
  ws[t] = s1;
  __syncthreads();
  for (int off = 1; off < 256; off <<= 1) {
    int u = (t >= off) ? ws[t - off] : 0;
    __syncthreads();
    ws[t] += u;
    __syncthreads();
  }
  int base = (t == 0) ? 0 : ws[t - 1];
  ((int2*)row)[t] = make_int2(base, base + s0);
  if (t == 255) btot[b] = ws[255];
}

// ---- pass 2: direct partitioned scatter, u32-packed (dl:9 | src:23) --------

__global__ __launch_bounds__(256) void k_part2(const int* __restrict__ ei, int e, int n,
    int nb, const int* __restrict__ pcnt, const int* __restrict__ btot,
    unsigned* __restrict__ ebuf) {
  __shared__ int se[256];
  __shared__ int base_l[256];
  __shared__ int cur[256];
  __shared__ int sflag;
  const int t = threadIdx.x;
  if (t == 0) sflag = 0;
  se[t] = (t < nb) ? btot[t] : 0;
  __syncthreads();
  for (int off = 1; off < 256; off <<= 1) {
    int u = (t >= off) ? se[t - off] : 0;
    __syncthreads();
    se[t] += u;
    __syncthreads();
  }
  if (t < nb) {
    int eb = (t == 0) ? 0 : se[t - 1];
    base_l[t] = eb + pcnt[(size_t)t * NPB + blockIdx.x];
    cur[t] = 0;
  }
  const int chunk = (e + NPB - 1) / NPB;
  const int lo = blockIdx.x * chunk;
  const int hi = min(lo + chunk, e);
  {
    int lim = min(hi, lo + 512);
    int f = 0;
    for (int i = lo + t; i < lim; i += 256)
      if (ei[2 * i + 1] != 0) f = 1;
    if (f) sflag = 1;
  }
  __syncthreads();
  const int f = sflag;
  for (int i = lo + t; i < hi; i += 256) {
    int s, d;
    if (f) {
      s = __builtin_nontemporal_load(&ei[i]);
      d = __builtin_nontemporal_load(&ei[e + i]);
    } else {
      s = (int)__builtin_nontemporal_load(&((const long long*)ei)[i]);
      d = (int)__builtin_nontemporal_load(&((const long long*)ei)[e + i]);
    }
    s = min(max(s, 0), n - 1);
    d = min(max(d, 0), n - 1);
    int b = d >> BSHIFT;
    int slot = atomicAdd(&cur[b], 1);
    ebuf[base_l[b] + slot] = ((unsigned)(d & (BW - 1)) << 23) | (unsigned)s;
  }
}

// ---- per-bucket finalize: degree, scan, row_ptr, dinv, col scatter, xs -----

__global__ __launch_bounds__(256) void k_finalize(const unsigned* __restrict__ ebuf,
    const int* __restrict__ btot, const float* __restrict__ x,
    unsigned short* __restrict__ xs, int n, int nb,
    int* __restrict__ row_ptr, float* __restrict__ dinv, int* __restrict__ col) {
  __shared__ int se[256], sc[256];
  __shared__ int ldeg[BW];
  __shared__ int lofs[BW];
  __shared__ int lcur[BW];
  __shared__ float sdv[BW];
  __shared__ int wsum[256];
  const int b = blockIdx.x;
  const int t = threadIdx.x;
  int bc = 0, nodes = 0;
  if (t < nb) {
    bc = btot[t];
    nodes = min(BW, n - t * BW);
  }
  se[t] = bc; sc[t] = bc + nodes;
  __syncthreads();
  for (int off = 1; off < 256; off <<= 1) {
    int ve = (t >= off) ? se[t - off] : 0;
    int vc = (t >= off) ? sc[t - off] : 0;
    __syncthreads();
    se[t] += ve; sc[t] += vc;
    __syncthreads();
  }
  const int eb = (b == 0) ? 0 : se[b - 1];
  const int ee = se[b];
  const int cb = (b == 0) ? 0 : sc[b - 1];
  const int lo = b * BW;
  const int nn = min(BW, n - lo);
  for (int k = t; k < BW; k += 256) ldeg[k] = 0;
  __syncthreads();
  for (int k = t; k < nn; k += 256) ldeg[k] = 1;  // self-loop
  __syncthreads();
  for (int j = eb + t; j < ee; j += 256) {
    int dl = (int)(ebuf[j] >> 23);
    atomicAdd(&ldeg[dl], 1);
  }
  __syncthreads();
  int p0 = ldeg[2 * t], p1 = ldeg[2 * t + 1];
  wsum[t] = p0 + p1;
  __syncthreads();
  for (int off = 1; off < 256; off <<= 1) {
    int v = (t >= off) ? wsum[t - off] : 0;
    __syncthreads();
    wsum[t] += v;
    __syncthreads();
  }
  int pb = (t == 0) ? 0 : wsum[t - 1];
  lofs[2 * t] = pb;
  lofs[2 * t + 1] = pb + p0;
  __syncthreads();
  for (int k = t; k < nn; k += 256) {
    int base = cb + lofs[k];
    float dv = rsqrtf((float)ldeg[k]);
    row_ptr[lo + k] = base;
    dinv[lo + k] = dv;
    sdv[k] = dv;
    col[base] = lo + k;          // self-loop entry
    lcur[k] = lofs[k] + 1;
  }
  if (b == nb - 1 && t == 0) row_ptr[n] = sc[nb - 1];
  __syncthreads();
  for (int j = eb + t; j < ee; j += 256) {
    unsigned pk = ebuf[j];
    int s = (int)(pk & 0x7FFFFF);
    int dl = (int)(pk >> 23);
    int p = atomicAdd(&lcur[dl], 1);
    col[cb + p] = s;
  }
  // fused k_scale: xs[row] = bf16(x[row] * dinv[row]) for this bucket's rows
  const float4* x4 = (const float4*)x;
  for (int idx = t; idx < nn * 16; idx += 256) {
    int row = idx >> 4, q = idx & 15;
    float sc2 = sdv[row];
    float4 v = x4[(size_t)(lo + row) * 16 + q];
    ushort4 o;
    o.x = f2bf(v.x * sc2); o.y = f2bf(v.y * sc2);
    o.z = f2bf(v.z * sc2); o.w = f2bf(v.w * sc2);
    ((ushort4*)xs)[(size_t)(lo + row) * 16 + q] = o;
  }
}

// ---- aggregation: 8 lanes/edge x 16B, 8 slots, depth-4, pk_add converts ----
// feat must have a zero row at index n.

template<bool BIAS, bool OUT_BF16>
__global__ __launch_bounds__(256) void k_agg(const unsigned short* __restrict__ feat,
    const int* __restrict__ row_ptr, const int* __restrict__ col,
    const float* __restrict__ dinv, const float* __restrict__ bias,
    void* __restrict__ outv, int n) {
  const int wid = threadIdx.x >> 6;
  const int lane = threadIdx.x & 63;
  const int es = lane >> 3;      // edge slot 0..7
  const int c8 = lane & 7;       // 16B channel chunk (8 ch)
  const int d = blockIdx.x * 4 + wid;
  if (d >= n) return;
  const int beg = row_ptr[d], end = row_ptr[d + 1];
  const uint4* f16 = (const uint4*)feat;   // row stride = 8 chunks
  const int rem = end - beg - es;
  const int c = (rem > 0) ? ((rem + 7) >> 3) : 0;
  const int last = end - 1;
  v2f a0 = {0.f, 0.f}, a1 = {0.f, 0.f}, a2 = {0.f, 0.f}, a3 = {0.f, 0.f};
  for (int g = 0; g < c; g += 4) {
    int j0 = beg + es + 8 * g;
    int i0 = col[j0];
    int i1 = col[min(j0 + 8, last)];
    int i2 = col[min(j0 + 16, last)];
    int i3 = col[min(j0 + 24, last)];
    if (g + 1 >= c) i1 = n;
    if (g + 2 >= c) i2 = n;
    if (g + 3 >= c) i3 = n;
    uint4 u0 = f16[(size_t)i0 * 8 + c8];
    uint4 u1 = f16[(size_t)i1 * 8 + c8];
    uint4 u2 = f16[(size_t)i2 * 8 + c8];
    uint4 u3 = f16[(size_t)i3 * 8 + c8];
    a0 += cvt2(u0.x) + cvt2(u1.x) + cvt2(u2.x) + cvt2(u3.x);
    a1 += cvt2(u0.y) + cvt2(u1.y) + cvt2(u2.y) + cvt2(u3.y);
    a2 += cvt2(u0.z) + cvt2(u1.z) + cvt2(u2.z) + cvt2(u3.z);
    a3 += cvt2(u0.w) + cvt2(u1.w) + cvt2(u2.w) + cvt2(u3.w);
  }
#pragma unroll
  for (int off = 8; off <= 32; off <<= 1) {
    v2f o0, o1, o2, o3;
    o0.x = __shfl_xor(a0.x, off); o0.y = __shfl_xor(a0.y, off);
    o1.x = __shfl_xor(a1.x, off); o1.y = __shfl_xor(a1.y, off);
    o2.x = __shfl_xor(a2.x, off); o2.y = __shfl_xor(a2.y, off);
    o3.x = __shfl_xor(a3.x, off); o3.y = __shfl_xor(a3.y, off);
    a0 += o0; a1 += o1; a2 += o2; a3 += o3;
  }
  if (es == 0) {
    float sc = dinv[d];
    v2f vs = {sc, sc};
    a0 *= vs; a1 *= vs; a2 *= vs; a3 *= vs;
    if (BIAS) {
      const v2f* b2v = (const v2f*)bias;
      a0 += b2v[c8 * 4 + 0]; a1 += b2v[c8 * 4 + 1];
      a2 += b2v[c8 * 4 + 2]; a3 += b2v[c8 * 4 + 3];
    }
    if (OUT_BF16) {
      uint4 o;
      o.x = pack2(a0); o.y = pack2(a1); o.z = pack2(a2); o.w = pack2(a3);
      ((uint4*)outv)[(size_t)d * 8 + c8] = o;
    } else {
      float4* o4 = (float4*)outv;
      o4[(size_t)d * 16 + c8 * 2]     = make_float4(a0.x, a0.y, a1.x, a1.y);
      o4[(size_t)d * 16 + c8 * 2 + 1] = make_float4(a2.x, a2.y, a3.x, a3.y);
    }
  }
}

// ---- fused MLP: h2s = (relu(A1 @ Wt1^T + b1) * dinv) @ Wt2^T, all bf16 -----
// block = 16 rows, 4 waves; gemm1 tile staged in LDS (pad 136 -> 2-way free)

__global__ __launch_bounds__(256) void k_mlp(const unsigned short* __restrict__ A1,
    const unsigned short* __restrict__ Wt1, const unsigned short* __restrict__ Wt2,
    const float* __restrict__ b1, const float* __restrict__ dinv,
    unsigned short* __restrict__ h2s, int M) {
  __shared__ unsigned short sA[16 * 136];
  const int wv = threadIdx.x >> 6;
  const int lane = threadIdx.x & 63;
  const int m = lane & 15;
  const int q = lane >> 4;
  const int r0 = blockIdx.x * 16;
  const int ra = min(r0 + m, M - 1);
  // GEMM1: C1[16][128]; wave wv covers col-tiles wv and wv+4
  f32x4 acc0 = {0.f, 0.f, 0.f, 0.f}, acc1 = {0.f, 0.f, 0.f, 0.f};
#pragma unroll
  for (int kt = 0; kt < IN_C; kt += 32) {
    bf16x8 a  = *(const bf16x8*)&A1[(size_t)ra * IN_C + kt + q * 8];
    bf16x8 p  = *(const bf16x8*)&Wt1[(size_t)(wv * 16 + m) * IN_C + kt + q * 8];
    bf16x8 p2 = *(const bf16x8*)&Wt1[(size_t)((wv + 4) * 16 + m) * IN_C + kt + q * 8];
    acc0 = __builtin_amdgcn_mfma_f32_16x16x32_bf16(a, p, acc0, 0, 0, 0);
    acc1 = __builtin_amdgcn_mfma_f32_16x16x32_bf16(a, p2, acc1, 0, 0, 0);
  }
  float dv[4];
#pragma unroll
  for (int i = 0; i < 4; i++) dv[i] = dinv[min(r0 + q * 4 + i, M - 1)];
  {
    int c = wv * 16 + m;
    float bv = b1[c];
#pragma unroll
    for (int i = 0; i < 4; i++)
      sA[(q * 4 + i) * 136 + c] = f2bf(fmaxf(acc0[i] + bv, 0.f) * dv[i]);
    c = (wv + 4) * 16 + m;
    bv = b1[c];
#pragma unroll
    for (int i = 0; i < 4; i++)
      sA[(q * 4 + i) * 136 + c] = f2bf(fmaxf(acc1[i] + bv, 0.f) * dv[i]);
  }
  __syncthreads();
  // GEMM2: C2[16][64]; wave wv covers cols wv*16..+15
  f32x4 acc = {0.f, 0.f, 0.f, 0.f};
#pragma unroll
  for (int kt = 0; kt < HID_C; kt += 32) {
    bf16x8 a = *(const bf16x8*)&sA[m * 136 + kt + q * 8];
    bf16x8 p = *(const bf16x8*)&Wt2[(size_t)(wv * 16 + m) * HID_C + kt + q * 8];
    acc = __builtin_amdgcn_mfma_f32_16x16x32_bf16(a, p, acc, 0, 0, 0);
  }
  int c = wv * 16 + m;
#pragma unroll
  for (int i = 0; i < 4; i++) {
    int row = r0 + q * 4 + i;
    if (row < M) h2s[(size_t)row * OUT_C + c] = f2bf(acc[i]);
  }
}

// ---- launch ---------------------------------------------------------------

extern "C" void kernel_launch(void* const* d_in, const int* in_sizes, int n_in,
                              void* d_out, int out_size, void* d_ws, size_t ws_size,
                              hipStream_t stream) {
  const float* x  = (const float*)d_in[0];
  const int*   ei = (const int*)d_in[1];
  const float* W1 = (const float*)d_in[2];
  const float* b1 = (const float*)d_in[3];
  const float* W2 = (const float*)d_in[4];
  const float* b2 = (const float*)d_in[5];
  float* out = (float*)d_out;

  const int n = in_sizes[0] / IN_C;   // 100000
  const int e = in_sizes[1] / 2;      // 3200000
  const int nb = (n + BW - 1) >> BSHIFT;  // 196 (must be <= 256)

  char* p = (char*)d_ws;
  auto alloc = [&](size_t bytes) {
    char* r = p;
    p += (bytes + 255) & ~(size_t)255;
    return r;
  };
  int*   pcnt       = (int*)alloc((size_t)nb * NPB * 4);
  int*   btot       = (int*)alloc((size_t)nb * 4);
  int*   row_ptr    = (int*)alloc((size_t)(n + 1) * 4);
  float* dinv       = (float*)alloc((size_t)n * 4);
  int*   col        = (int*)alloc((size_t)(e + n) * 4);
  unsigned* ebuf    = (unsigned*)alloc((size_t)e * 4);
  unsigned short* xs  = (unsigned short*)alloc((size_t)(n + 1) * IN_C * 2);   // + zero row
  unsigned short* A1  = (unsigned short*)alloc((size_t)n * IN_C * 2);
  unsigned short* h2s = (unsigned short*)alloc((size_t)(n + 1) * OUT_C * 2);  // + zero row
  unsigned short* Wt1 = (unsigned short*)alloc((size_t)IN_C * HID_C * 2);
  unsigned short* Wt2 = (unsigned short*)alloc((size_t)HID_C * OUT_C * 2);

  // CSR build + weights + zero rows (part1 extras)
  k_part1<<<NPB + 33, 256, nb * 4, stream>>>(ei, e, n, nb, pcnt, W1, W2, Wt1, Wt2,
      xs + (size_t)n * IN_C, h2s + (size_t)n * OUT_C);
  k_bscan<<<nb, 256, 0, stream>>>(pcnt, btot);
  k_part2<<<NPB, 256, 0, stream>>>(ei, e, n, nb, pcnt, btot, ebuf);
  k_finalize<<<nb, 256, 0, stream>>>(ebuf, btot, x, xs, n, nb, row_ptr, dinv, col);

  // Layer 1 aggregate -> bf16 A1; fused MLP -> bf16 h2s; layer 2 aggregate
  k_agg<false, true><<<(n + 3) / 4, 256, 0, stream>>>(xs, row_ptr, col, dinv, nullptr, A1, n);
  k_mlp<<<(n + 15) / 16, 256, 0, stream>>>(A1, Wt1, Wt2, b1, dinv, h2s, n);
  k_agg<true, false><<<(n + 3) / 4, 256, 0, stream>>>(h2s, row_ptr, col, dinv, b2, out, n);
}